// Round 9
// baseline (367.451 us; speedup 1.0000x reference)
//
#include <hip/hip_runtime.h>
#include <cstdint>
#include <cstddef>

// ---------------------------------------------------------------------------
// Hyena operator, MI355X.
//  cast(u,W1,W2)->bf16 ; GEMM1 (bf16 MFMA, writes upT[1152][16384] bf16 +bias)
//  tw_init: twiddle tables W_8192^(jk), W_512^(jk), W_32^(jk) -> 64 KB global
//           (shared by all FFT blocks; L2-resident; kills per-trip sincos +
//            15-step serial cmul chain that stalled the 2-wave/SIMD kernel).
//  fft_k: per channel, 8192-pt complex FFT of even/odd-packed real kernel;
//         Hermitian-split -> P,Q tables (fp16, slot order) incl. conv_bias.
//  fftconv_split: per (batch,channel): pack z[m]=v[2m]+i*v[2m+1] (depthwise
//         conv3 + pre-gate fused, scaled 1/8192) -> 3 radix-16 DIF trips ->
//         fused [radix2-fwd -> T = Z*P + conj(Zpair)*Q -> radix2-inv] ->
//         3 radix-16 DIT trips -> finalize (post-gate x0) -> z bf16. 64 KB LDS.
//  transpose z -> zt ; GEMM2 (bf16 MFMA, f32 out+bias) -> d_out
// Register discipline (hard-won): 512 threads/block, NO waves_per_eu and NO
// 1024-thread blocks — both force a 64-VGPR budget -> ~260 MB scratch spills
// (proven rounds 2/4/5/7).
// ---------------------------------------------------------------------------

using s16x8 = __attribute__((ext_vector_type(8))) short;
using f32x4 = __attribute__((ext_vector_type(4))) float;

__device__ __forceinline__ float bfu2f(unsigned short h) {
  union { unsigned int u; float f; } a; a.u = ((unsigned int)h) << 16; return a.f;
}
__device__ __forceinline__ unsigned short f2bf(float f) {
  union { float f; unsigned int u; } a; a.f = f;
  unsigned int r = a.u + 0x7fffu + ((a.u >> 16) & 1u);
  return (unsigned short)(r >> 16);
}
__device__ __forceinline__ unsigned f2h2(float x, float y) {
  union { _Float16 h[2]; unsigned u; } v;
  v.h[0] = (_Float16)x; v.h[1] = (_Float16)y; return v.u;
}
__device__ __forceinline__ float2 h2f2(unsigned u) {
  union { unsigned u; _Float16 h[2]; } v; v.u = u;
  return make_float2((float)v.h[0], (float)v.h[1]);
}
__device__ __forceinline__ float2 cmul(float2 a, float2 b) {
  return make_float2(a.x*b.x - a.y*b.y, a.x*b.y + a.y*b.x);
}
// a * conj(w)
__device__ __forceinline__ float2 cmulcj(float2 a, float2 w) {
  return make_float2(a.x*w.x + a.y*w.y, a.y*w.x - a.x*w.y);
}
__device__ __forceinline__ float2 cmulc(float2 a, float cr, float ci) {
  return make_float2(a.x*cr - a.y*ci, a.x*ci + a.y*cr);
}
__device__ __forceinline__ float2 cadd(float2 a, float2 b) { return make_float2(a.x+b.x, a.y+b.y); }
__device__ __forceinline__ float2 csub(float2 a, float2 b) { return make_float2(a.x-b.x, a.y-b.y); }
__device__ __forceinline__ float2 conjf(float2 a) { return make_float2(a.x, -a.y); }
// LDS bank swizzle at float2 granularity (involution, bits 4..7 preserved).
__device__ __forceinline__ int SW(int p) { return p ^ ((p >> 4) & 15); }
// 3-nibble reverse: slot<->frequency map for the [16,16,16,2] digit-reversed
// DIF layout (slot 2t holds freq nibrev3(t)).
__device__ __forceinline__ int nibrev3(int x) {
  return ((x & 15) << 8) | (x & 0xF0) | ((x >> 8) & 15);
}

#define TWOPI 6.2831853071795864769f
// twiddle table offsets (float2 units): TA 15x512, TB 15x32, TC 15x2
#define TWB_OFF 7680
#define TWC_OFF 8160
#define TW_TOTAL 8190

// ---------------- twiddle table init (runs once, 64 KB) ----------------
__global__ __launch_bounds__(512)
void tw_init_kernel(float2* __restrict__ tw) {
  const int i = blockIdx.x * 512 + threadIdx.x;
  float sn = 0.f, cs = 1.f;
  if (i < TWB_OFF) {                    // TA: W_8192^(k*j), k=1..15, j=0..511
    const int k = (i >> 9) + 1, j = i & 511;
    sincosf(-TWOPI * (float)(k * j) / 8192.0f, &sn, &cs);
    tw[i] = make_float2(cs, sn);
  } else if (i < TWC_OFF) {             // TB: W_512^(k*j), j=0..31
    const int b = i - TWB_OFF;
    const int k = (b >> 5) + 1, j = b & 31;
    sincosf(-TWOPI * (float)(k * j) / 512.0f, &sn, &cs);
    tw[i] = make_float2(cs, sn);
  } else if (i < TW_TOTAL) {            // TC: W_32^(k*j), j=0..1
    const int b = i - TWC_OFF;
    const int k = (b >> 1) + 1, j = b & 1;
    sincosf(-TWOPI * (float)(k * j) / 32.0f, &sn, &cs);
    tw[i] = make_float2(cs, sn);
  }
}

// ---------------- cast f32 -> bf16 ----------------
__global__ __launch_bounds__(256)
void cast_f32_to_bf16(const float* __restrict__ src, unsigned short* __restrict__ dst, const int n) {
  const int i = (blockIdx.x * 256 + threadIdx.x) * 4;
  if (i < n) {
    const float4 v = *(const float4*)(src + i);
    ushort4 o;
    o.x = f2bf(v.x); o.y = f2bf(v.y); o.z = f2bf(v.z); o.w = f2bf(v.w);
    *(ushort4*)(dst + i) = o;
  }
}

// ---------------- bf16 GEMM: C[m][n] = sum_k A[m][k]*B[n][k] + bias[n] ------
template<int TRANS>
__global__ __launch_bounds__(256)
void gemm_bt(const unsigned short* __restrict__ A, const unsigned short* __restrict__ B,
             const float* __restrict__ bias, void* __restrict__ Cout,
             const int M, const int N, const int K) {
  __shared__ unsigned short As[128 * 32];
  __shared__ unsigned short Bs[128 * 32];
  const int tid  = threadIdx.x;
  const int lane = tid & 63;
  const int wave = tid >> 6;
  const int m0 = blockIdx.x * 128;
  const int n0 = blockIdx.y * 128;
  const int wm = (wave >> 1) * 64;
  const int wn = (wave & 1) * 64;
  f32x4 acc[4][4] = {};

  const int srow = lane >> 2;
  const int scol = (lane & 3) * 8;

  for (int k0 = 0; k0 < K; k0 += 32) {
    __syncthreads();
#pragma unroll
    for (int pass = 0; pass < 2; ++pass) {
      const int rbase = pass * 64 + wave * 16;
      const unsigned short* ga = A + (size_t)(m0 + rbase + srow) * K + k0 + scol;
      const unsigned short* gb = B + (size_t)(n0 + rbase + srow) * K + k0 + scol;
      __builtin_amdgcn_global_load_lds((__attribute__((address_space(1))) void*)ga,
                                       (__attribute__((address_space(3))) void*)(As + rbase * 32), 16, 0, 0);
      __builtin_amdgcn_global_load_lds((__attribute__((address_space(1))) void*)gb,
                                       (__attribute__((address_space(3))) void*)(Bs + rbase * 32), 16, 0, 0);
    }
    __syncthreads();
    s16x8 af[4], bfr[4];
#pragma unroll
    for (int i = 0; i < 4; ++i) {
      af[i]  = *(const s16x8*)(As + (wm + i * 16 + (lane & 15)) * 32 + (lane >> 4) * 8);
      bfr[i] = *(const s16x8*)(Bs + (wn + i * 16 + (lane & 15)) * 32 + (lane >> 4) * 8);
    }
#pragma unroll
    for (int mi = 0; mi < 4; ++mi)
#pragma unroll
      for (int ni = 0; ni < 4; ++ni)
        acc[mi][ni] = __builtin_amdgcn_mfma_f32_16x16x32_bf16(af[mi], bfr[ni], acc[mi][ni], 0, 0, 0);
  }
#pragma unroll
  for (int mi = 0; mi < 4; ++mi) {
#pragma unroll
    for (int ni = 0; ni < 4; ++ni) {
      const int col  = n0 + wn + ni * 16 + (lane & 15);
      const int row0 = m0 + wm + mi * 16 + (lane >> 4) * 4;
      const float bv = bias[col];
      if (TRANS) {
        unsigned short* Ct = (unsigned short*)Cout;
        ushort4 o;
        o.x = f2bf(acc[mi][ni][0] + bv);
        o.y = f2bf(acc[mi][ni][1] + bv);
        o.z = f2bf(acc[mi][ni][2] + bv);
        o.w = f2bf(acc[mi][ni][3] + bv);
        *(ushort4*)(Ct + (size_t)col * M + row0) = o;
      } else {
        float* C = (float*)Cout;
#pragma unroll
        for (int rr = 0; rr < 4; ++rr)
          C[(size_t)(row0 + rr) * N + col] = acc[mi][ni][rr] + bv;
      }
    }
  }
}

// =================== radix-16 FFT building blocks ===========================
template<int SGN>   // -1: fwd, +1: inv
__device__ __forceinline__ void dft4(float2& a, float2& b, float2& c, float2& d) {
  const float2 t0 = cadd(a, c), t1 = csub(a, c);
  const float2 t2 = cadd(b, d), t3 = csub(b, d);
  const float2 jt3 = (SGN < 0) ? make_float2(t3.y, -t3.x) : make_float2(-t3.y, t3.x);
  a = cadd(t0, t2);
  c = csub(t0, t2);
  b = cadd(t1, jt3);
  d = csub(t1, jt3);
}
template<int SGN>
__device__ __forceinline__ void dft4_half(float2& a, float2& b, float2& c, float2& d) {
  const float2 a0 = a, b0 = b;
  const float2 jb = (SGN < 0) ? make_float2(b0.y, -b0.x) : make_float2(-b0.y, b0.x);
  a = cadd(a0, b0);
  c = csub(a0, b0);
  b = cadd(a0, jb);
  d = csub(a0, jb);
}
template<int SGN>
__device__ __forceinline__ void dft4_lo(float2& a, float2& b, const float2 c, const float2 d) {
  const float2 t0 = cadd(a, c), t1 = csub(a, c);
  const float2 t2 = cadd(b, d), t3 = csub(b, d);
  const float2 jt3 = (SGN < 0) ? make_float2(t3.y, -t3.x) : make_float2(-t3.y, t3.x);
  a = cadd(t0, t2);
  b = cadd(t1, jt3);
}

// 16-point DFT, 4x4 decomposition. Input x_m at y[m]; output X[k] is read
// back via y[4*(k&3) + (k>>2)] (digit swap undone by callers).
template<int SGN, bool HALFIN, bool LO8>
__device__ __forceinline__ void dft16_core(float2* y) {
#pragma unroll
  for (int m0 = 0; m0 < 4; ++m0) {
    if (HALFIN) dft4_half<SGN>(y[m0], y[4+m0], y[8+m0], y[12+m0]);
    else        dft4<SGN>(y[m0], y[4+m0], y[8+m0], y[12+m0]);
  }
  const float sg = (SGN < 0) ? -1.f : 1.f;
  const float C_ = 0.92387953251128675613f;
  const float S_ = 0.38268343236508977173f;
  const float R_ = 0.70710678118654752440f;
  y[5]  = cmulc(y[5],  C_,  sg*S_);
  y[6]  = cmulc(y[6],  R_,  sg*R_);
  y[7]  = cmulc(y[7],  S_,  sg*C_);
  y[9]  = cmulc(y[9],  R_,  sg*R_);
  y[10] = (SGN < 0) ? make_float2(y[10].y, -y[10].x) : make_float2(-y[10].y, y[10].x);
  y[11] = cmulc(y[11], -R_, sg*R_);
  y[13] = cmulc(y[13], S_,  sg*C_);
  y[14] = cmulc(y[14], -R_, sg*R_);
  y[15] = cmulc(y[15], -C_, -sg*S_);
#pragma unroll
  for (int k0 = 0; k0 < 4; ++k0) {
    if (LO8) dft4_lo<SGN>(y[4*k0], y[4*k0+1], y[4*k0+2], y[4*k0+3]);
    else     dft4<SGN>(y[4*k0], y[4*k0+1], y[4*k0+2], y[4*k0+3]);
  }
}

// 8192-pt trips, 512 threads, table-driven twiddles (TW layout [k-1][2^LOGS]).
template<int LOGS, int LOGM>
__device__ __forceinline__ void t8_fwd_tw(float2* __restrict__ buf, const int tid,
                                          const float2* __restrict__ TW) {
  const int j = tid & ((1 << LOGS) - 1);
  const int base = ((tid >> LOGS) << LOGM) + j;
  float2 y[16];
#pragma unroll
  for (int m = 0; m < 16; ++m) y[m] = buf[SW(base + (m << LOGS))];
  dft16_core<-1, false, false>(y);
  buf[SW(base)] = y[0];
#pragma unroll
  for (int k = 1; k < 16; ++k)
    buf[SW(base + (k << LOGS))] = cmul(y[4*(k&3) + (k>>2)], TW[(k-1)*(1 << LOGS) + j]);
}
template<int LOGS, int LOGM>
__device__ __forceinline__ void t8_inv_tw(float2* __restrict__ buf, const int tid,
                                          const float2* __restrict__ TW) {
  const int j = tid & ((1 << LOGS) - 1);
  const int base = ((tid >> LOGS) << LOGM) + j;
  float2 y[16];
  y[0] = buf[SW(base)];
#pragma unroll
  for (int k = 1; k < 16; ++k)
    y[k] = cmulcj(buf[SW(base + (k << LOGS))], TW[(k-1)*(1 << LOGS) + j]);
  dft16_core<1, false, false>(y);
#pragma unroll
  for (int m = 0; m < 16; ++m)
    buf[SW(base + (m << LOGS))] = y[4*(m&3) + (m>>2)];
}
// trip A fwd (S=512, M=8192), input y[0..7] from regs, upper half zero.
__device__ __forceinline__ void t8_A_fwd_reg_tw(float2* __restrict__ buf, const int tid,
                                                float2* y, const float2* __restrict__ TA) {
  dft16_core<-1, true, false>(y);
  buf[SW(tid)] = y[0];
#pragma unroll
  for (int k = 1; k < 16; ++k)
    buf[SW(tid + (k << 9))] = cmul(y[4*(k&3) + (k>>2)], TA[(k-1)*512 + tid]);
}

// ---------------- fft_k: P,Q tables from 8192-pt rfft of kernel -------------
// z[m] = k[2m] + i*k[2m+1] (free pack: raw float2 load). After DIF trips
// (pre-final-radix2), slot pair (2t,2t+1) = freqs (k0, k0+4096), k0=nibrev3(t).
// P(k) = E(k)+cb - s_k*F(k), Q(k) = i*c_k*F(k), F = W16384^k * O(k),
// E=(Z+conj(Zpair))/2, O=(Z-conj(Zpair))/(2i). Stored fp16 at slot index.
__global__ __launch_bounds__(512)
void fft_k_kernel(const float* __restrict__ kmat, const float* __restrict__ conv_bias,
                  uint2* __restrict__ G, const float2* __restrict__ tw) {
  __shared__ float2 buf[8192];                               // 64 KB
  const int tid = threadIdx.x;
  const int c   = blockIdx.x;
  const float* kr = kmat + (size_t)c * 8192;
  {
    float2 y[16];
#pragma unroll
    for (int r = 0; r < 8; ++r) y[r] = *(const float2*)(kr + 2 * (tid + (r << 9)));
    t8_A_fwd_reg_tw(buf, tid, y, tw);
  }
  __syncthreads();
  t8_fwd_tw<5, 9>(buf, tid, tw + TWB_OFF);
  __syncthreads();
  t8_fwd_tw<1, 5>(buf, tid, tw + TWC_OFF);
  __syncthreads();
  const float cb = conv_bias[c];
  uint2* Gt = G + (size_t)c * 8192;
#pragma unroll 1
  for (int i = 0; i < 8; ++i) {
    const int t  = tid + (i << 9);
    const int k0 = nibrev3(t);
    const float2 La = buf[SW(2 * t)], Lb = buf[SW(2 * t + 1)];
    const float2 Z0 = cadd(La, Lb), Z1 = csub(La, Lb);   // freqs k0, k0+4096
    float2 Zt0, Zt1;                                      // conj pairs
    if (t == 0) { Zt0 = conjf(Z0); Zt1 = conjf(Z1); }
    else {
      const int tp = nibrev3((8192 - k0) & 4095);
      const float2 Lc = buf[SW(2 * tp)], Ld = buf[SW(2 * tp + 1)];
      Zt0 = conjf(csub(Lc, Ld));   // conj(Z[8192-k0])
      Zt1 = conjf(cadd(Lc, Ld));   // conj(Z[4096-k0])
    }
    float sn, cs;
    __sincosf((float)k0 * (TWOPI / 16384.0f), &sn, &cs);
    // freq k0: W = (cs,-sn)
    const float2 E0 = make_float2(0.5f * (Z0.x + Zt0.x), 0.5f * (Z0.y + Zt0.y));
    const float2 d0 = csub(Z0, Zt0);
    const float2 O0 = make_float2(0.5f * d0.y, -0.5f * d0.x);
    const float2 F0 = cmul(make_float2(cs, -sn), O0);
    const float2 P0 = make_float2(E0.x + cb - sn * F0.x, E0.y - sn * F0.y);
    const float2 Q0 = make_float2(-cs * F0.y, cs * F0.x);
    // freq k0+4096: s->cs, c->-sn, W -> (-sn,-cs)
    const float2 E1 = make_float2(0.5f * (Z1.x + Zt1.x), 0.5f * (Z1.y + Zt1.y));
    const float2 d1 = csub(Z1, Zt1);
    const float2 O1 = make_float2(0.5f * d1.y, -0.5f * d1.x);
    const float2 F1 = cmul(make_float2(-sn, -cs), O1);
    const float2 P1 = make_float2(E1.x + cb - cs * F1.x, E1.y - cs * F1.y);
    const float2 Q1 = make_float2(sn * F1.y, -sn * F1.x);
    uint4 o;
    o.x = f2h2(P0.x, P0.y); o.y = f2h2(Q0.x, Q0.y);
    o.z = f2h2(P1.x, P1.y); o.w = f2h2(Q1.x, Q1.y);
    *(uint4*)(Gt + 2 * t) = o;                            // coalesced, linear
  }
}

// ---------------- main fused kernel (per batch x channel) -------------------
__global__ __launch_bounds__(512)
void hyena_fftconv_split(const unsigned short* __restrict__ upT,  // [1152][16384]
                         const uint2* __restrict__ G,              // P,Q fp16
                         const float* __restrict__ short_w,
                         const float* __restrict__ short_b,
                         const float2* __restrict__ tw,
                         unsigned short* __restrict__ z) {          // [3072][8192]
  __shared__ float2 buf[8192];                               // 64 KB
  const int tid = threadIdx.x;
  const int c   = blockIdx.y;
  const int bat = blockIdx.x;

  // ---- pack: depthwise conv3 + pre-gate; z[m] = v[2m] + i*v[2m+1], /8192 ---
  const int c0 = c % 1152;
  const int c1 = (c + 384) % 1152;
  const int c2 = (c + 768) % 1152;
  const unsigned short* r0 = upT + (size_t)c0 * 16384 + bat * 8192;
  const unsigned short* r1 = upT + (size_t)c1 * 16384 + bat * 8192;
  const unsigned short* r2 = upT + (size_t)c2 * 16384 + bat * 8192;
  float w0[3], w1v[3], w2v[3];
#pragma unroll
  for (int j = 0; j < 3; ++j) {
    w0[j]  = short_w[(size_t)c * 3 + j];
    w1v[j] = short_w[(size_t)(1536 + c) * 3 + j];
    w2v[j] = short_w[(size_t)(3072 + c) * 3 + j];
  }
  const float b0 = short_b[c], b1s = short_b[1536 + c], b2s = short_b[3072 + c];
  const float s = 1.0f / 8192.0f;
  float2 xy[8];
  unsigned x0p[8];   // packed bf16 post-gates (lo=even sample, hi=odd)
#pragma unroll
  for (int r = 0; r < 8; ++r) {
    const int m = tid + (r << 9);           // m < 4096
    const unsigned e0 = *(const unsigned*)(r0 + 2 * m);
    const unsigned e1 = *(const unsigned*)(r1 + 2 * m);
    const unsigned e2 = *(const unsigned*)(r2 + 2 * m);
    unsigned p0 = 0, p1 = 0, p2 = 0;
    if (m > 0) {
      p0 = *(const unsigned*)(r0 + 2 * m - 2);
      p1 = *(const unsigned*)(r1 + 2 * m - 2);
      p2 = *(const unsigned*)(r2 + 2 * m - 2);
    }
    const float u0a = bfu2f((unsigned short)(p0 & 0xffff)), u0b = bfu2f((unsigned short)(p0 >> 16));
    const float u0c = bfu2f((unsigned short)(e0 & 0xffff)), u0d = bfu2f((unsigned short)(e0 >> 16));
    const float u1a = bfu2f((unsigned short)(p1 & 0xffff)), u1b = bfu2f((unsigned short)(p1 >> 16));
    const float u1c = bfu2f((unsigned short)(e1 & 0xffff)), u1d = bfu2f((unsigned short)(e1 >> 16));
    const float u2a = bfu2f((unsigned short)(p2 & 0xffff)), u2b = bfu2f((unsigned short)(p2 >> 16));
    const float u2c = bfu2f((unsigned short)(e2 & 0xffff)), u2d = bfu2f((unsigned short)(e2 >> 16));
    const float x0e = b0  + w0[0]  * u0a + w0[1]  * u0b + w0[2]  * u0c;
    const float x0o = b0  + w0[0]  * u0b + w0[1]  * u0c + w0[2]  * u0d;
    const float x1e = b1s + w1v[0] * u1a + w1v[1] * u1b + w1v[2] * u1c;
    const float x1o = b1s + w1v[0] * u1b + w1v[1] * u1c + w1v[2] * u1d;
    const float vE  = b2s + w2v[0] * u2a + w2v[1] * u2b + w2v[2] * u2c;
    const float vO  = b2s + w2v[0] * u2b + w2v[1] * u2c + w2v[2] * u2d;
    xy[r] = make_float2(vE * x1e * s, vO * x1o * s);
    x0p[r] = (unsigned)f2bf(x0e) | ((unsigned)f2bf(x0o) << 16);
  }

  // ---- forward: trip A (regs, half-zero) + trips B, C ----
  {
    float2 y[16];
#pragma unroll
    for (int r = 0; r < 8; ++r) y[r] = xy[r];
    t8_A_fwd_reg_tw(buf, tid, y, tw);
  }
  __syncthreads();
  t8_fwd_tw<5, 9>(buf, tid, tw + TWB_OFF);
  __syncthreads();
  t8_fwd_tw<1, 5>(buf, tid, tw + TWC_OFF);
  __syncthreads();

  // ---- fused: radix2-fwd -> T = Z*P + conj(Zpair)*Q -> radix2-inv ----
  // Quads {2t,2t+1,2t',2t'+1} are disjoint; canonical owner (t <= t') writes.
  const uint2* Gt = G + (size_t)c * 8192;
#pragma unroll 1
  for (int i = 0; i < 8; ++i) {
    const int t  = tid + (i << 9);
    const int k0 = nibrev3(t);
    const float2 La = buf[SW(2 * t)], Lb = buf[SW(2 * t + 1)];
    const float2 Z0 = cadd(La, Lb), Z1 = csub(La, Lb);   // freqs k0, k0+4096
    if (t == 0) {
      const uint4 g = *(const uint4*)(Gt);
      const float2 T0 = cadd(cmul(Z0, h2f2(g.x)), cmul(conjf(Z0), h2f2(g.y)));
      const float2 T1 = cadd(cmul(Z1, h2f2(g.z)), cmul(conjf(Z1), h2f2(g.w)));
      buf[SW(0)] = cadd(T0, T1);
      buf[SW(1)] = csub(T0, T1);
      continue;
    }
    const int tp = nibrev3((8192 - k0) & 4095);
    if (tp < t) continue;
    const float2 Lc = buf[SW(2 * tp)], Ld = buf[SW(2 * tp + 1)];
    const float2 Z0p = cadd(Lc, Ld), Z1p = csub(Lc, Ld); // freqs 4096-k0, 8192-k0
    const uint4 ga = *(const uint4*)(Gt + 2 * t);        // P,Q at k0, k0+4096
    const uint4 gb = *(const uint4*)(Gt + 2 * tp);       // P,Q at 4096-k0, 8192-k0
    const float2 T0  = cadd(cmul(Z0,  h2f2(ga.x)), cmul(conjf(Z1p), h2f2(ga.y)));
    const float2 T1  = cadd(cmul(Z1,  h2f2(ga.z)), cmul(conjf(Z0p), h2f2(ga.w)));
    const float2 T0p = cadd(cmul(Z0p, h2f2(gb.x)), cmul(conjf(Z1),  h2f2(gb.y)));
    const float2 T1p = cadd(cmul(Z1p, h2f2(gb.z)), cmul(conjf(Z0),  h2f2(gb.w)));
    buf[SW(2 * t)]      = cadd(T0, T1);
    buf[SW(2 * t + 1)]  = csub(T0, T1);
    buf[SW(2 * tp)]     = cadd(T0p, T1p);
    buf[SW(2 * tp + 1)] = csub(T0p, T1p);
  }
  __syncthreads();

  // ---- inverse: trips C', B', then A' (regs, only m<4096 needed) ----
  t8_inv_tw<1, 5>(buf, tid, tw + TWC_OFF);
  __syncthreads();
  t8_inv_tw<5, 9>(buf, tid, tw + TWB_OFF);
  __syncthreads();
  {
    float2 y[16];
    y[0] = buf[SW(tid)];
#pragma unroll
    for (int k = 1; k < 16; ++k)
      y[k] = cmulcj(buf[SW(tid + (k << 9))], tw[(k-1)*512 + tid]);
    dft16_core<1, false, true>(y);
    unsigned short* za = z + (size_t)(bat * 1536 + c) * 8192;
#pragma unroll
    for (int r = 0; r < 8; ++r) {
      const int m = tid + (r << 9);
      const float2 F = y[4 * (r & 3) + (r >> 2)];       // t[m]: Re=y[2m], Im=y[2m+1]
      const float ga = bfu2f((unsigned short)(x0p[r] & 0xffff));
      const float gb = bfu2f((unsigned short)(x0p[r] >> 16));
      const unsigned o = (unsigned)f2bf(F.x * ga) | ((unsigned)f2bf(F.y * gb) << 16);
      *(unsigned*)(za + 2 * m) = o;
    }
  }
}

// =============== legacy radix-4 monolithic fallback (small ws) ==============
__device__ __forceinline__ void dif_bfly(float2* __restrict__ buf, const int p0, const int q,
                                         const float2 w1, const float2 w2) {
  float2 x0 = buf[SW(p0)];
  float2 x1 = buf[SW(p0 + q)];
  float2 x2 = buf[SW(p0 + 2 * q)];
  float2 x3 = buf[SW(p0 + 3 * q)];
  const float2 ta = cadd(x0, x2), tb = csub(x0, x2);
  const float2 ua = cadd(x1, x3), ub = csub(x1, x3);
  const float2 v02 = cmul(tb, w1);
  float2 v13 = cmul(ub, w1);
  v13 = make_float2(v13.y, -v13.x);
  buf[SW(p0)]         = cadd(ta, ua);
  buf[SW(p0 + q)]     = cmul(csub(ta, ua), w2);
  buf[SW(p0 + 2 * q)] = cadd(v02, v13);
  buf[SW(p0 + 3 * q)] = cmul(csub(v02, v13), w2);
}
__device__ __forceinline__ void dit_bfly(float2* __restrict__ buf, const int p0, const int q,
                                         const float2 w1, const float2 w2) {
  float2 x0 = buf[SW(p0)];
  float2 x1 = buf[SW(p0 + q)];
  float2 x2 = buf[SW(p0 + 2 * q)];
  float2 x3 = buf[SW(p0 + 3 * q)];
  const float2 t1 = cmul(x1, w2);
  const float2 y0 = cadd(x0, t1), y1 = csub(x0, t1);
  const float2 t3 = cmul(x3, w2);
  const float2 y2 = cadd(x2, t3), y3 = csub(x2, t3);
  const float2 t  = cmul(y2, w1);
  float2 t4 = cmul(y3, w1);
  t4 = make_float2(t4.y, -t4.x);
  buf[SW(p0)]         = cadd(y0, t);
  buf[SW(p0 + q)]     = cadd(y1, t4);
  buf[SW(p0 + 2 * q)] = csub(y0, t);
  buf[SW(p0 + 3 * q)] = csub(y1, t4);
}
template<int NTHR>
__device__ __forceinline__ void dif_fft(float2* __restrict__ buf, const int tid) {
  constexpr int ITERS = 4096 / NTHR;
  for (int r = 0; r < 7; ++r) {
    const int qs = 12 - 2 * r;
    const int q  = 1 << qs;
    const float angf = -TWOPI / (float)(4 << qs);
    if (q <= NTHR) {
      const int j = tid & (q - 1);
      float sn, cs; __sincosf(angf * (float)j, &sn, &cs);
      const float2 w1 = make_float2(cs, sn);
      const float2 w2 = cmul(w1, w1);
#pragma unroll
      for (int it = 0; it < ITERS; ++it) {
        const int id = tid + it * NTHR;
        const int p0 = ((id >> qs) << (qs + 2)) + j;
        dif_bfly(buf, p0, q, w1, w2);
      }
    } else {
#pragma unroll
      for (int it = 0; it < ITERS; ++it) {
        const int id = tid + it * NTHR;
        const int j  = id & (q - 1);
        const int p0 = ((id >> qs) << (qs + 2)) + j;
        float sn, cs; __sincosf(angf * (float)j, &sn, &cs);
        const float2 w1 = make_float2(cs, sn);
        dif_bfly(buf, p0, q, w1, cmul(w1, w1));
      }
    }
    __syncthreads();
  }
}
template<int NTHR>
__device__ __forceinline__ void dit_fft(float2* __restrict__ buf, const int tid) {
  constexpr int ITERS = 4096 / NTHR;
  for (int r = 0; r < 7; ++r) {
    const int qs = 2 * r;
    const int q  = 1 << qs;
    const float angf = -TWOPI / (float)(4 << qs);
    if (q <= NTHR) {
      const int j = tid & (q - 1);
      float sn, cs; __sincosf(angf * (float)j, &sn, &cs);
      const float2 w1 = make_float2(cs, sn);
      const float2 w2 = cmul(w1, w1);
#pragma unroll
      for (int it = 0; it < ITERS; ++it) {
        const int id = tid + it * NTHR;
        const int p0 = ((id >> qs) << (qs + 2)) + j;
        dit_bfly(buf, p0, q, w1, w2);
      }
    } else {
#pragma unroll
      for (int it = 0; it < ITERS; ++it) {
        const int id = tid + it * NTHR;
        const int j  = id & (q - 1);
        const int p0 = ((id >> qs) << (qs + 2)) + j;
        float sn, cs; __sincosf(angf * (float)j, &sn, &cs);
        const float2 w1 = make_float2(cs, sn);
        dit_bfly(buf, p0, q, w1, cmul(w1, w1));
      }
    }
    __syncthreads();
  }
}
__global__ __launch_bounds__(512)
void hyena_fftconv_mono(const unsigned short* __restrict__ upT,
                        const float* __restrict__ kmat,
                        const float* __restrict__ short_w,
                        const float* __restrict__ short_b,
                        const float* __restrict__ conv_bias,
                        unsigned short* __restrict__ z) {
  __shared__ float2 buf[16384];
  const int tid = threadIdx.x;
  const int c   = blockIdx.x;
  const float* kr = kmat + (size_t)c * 8192;
#pragma unroll
  for (int i = 0; i < 32; ++i) {
    const int n = tid + i * 512;
    float2 v = make_float2(0.f, 0.f);
    if (n < 8192) v.x = kr[n];
    buf[SW(n)] = v;
  }
  __syncthreads();
  dif_fft<512>(buf, tid);
  float2 kf[32];
#pragma unroll
  for (int i = 0; i < 32; ++i) kf[i] = buf[tid + i * 512];
  __syncthreads();
  const int c0 = c % 1152;
  const int c1 = (c + 384) % 1152;
  const int c2 = (c + 768) % 1152;
  const unsigned short* r0 = upT + (size_t)c0 * 16384;
  const unsigned short* r1 = upT + (size_t)c1 * 16384;
  const unsigned short* r2 = upT + (size_t)c2 * 16384;
  float w0[3], w1v[3], w2v[3];
#pragma unroll
  for (int j = 0; j < 3; ++j) {
    w0[j]  = short_w[(size_t)c * 3 + j];
    w1v[j] = short_w[(size_t)(1536 + c) * 3 + j];
    w2v[j] = short_w[(size_t)(3072 + c) * 3 + j];
  }
  const float b0 = short_b[c], b1s = short_b[1536 + c], b2s = short_b[3072 + c];
  float x0a[16], x0b[16], vpa[16], vpb[16];
#pragma unroll
  for (int i = 0; i < 16; ++i) {
    const int n = tid + i * 512;
    float s0a = b0, s1a = b1s, s2a = b2s;
    float s0b = b0, s1b = b1s, s2b = b2s;
#pragma unroll
    for (int j = 0; j < 3; ++j) {
      const int t = n - 2 + j;
      if (t >= 0) {
        s0a += w0[j]  * bfu2f(r0[t]);
        s1a += w1v[j] * bfu2f(r1[t]);
        s2a += w2v[j] * bfu2f(r2[t]);
        s0b += w0[j]  * bfu2f(r0[8192 + t]);
        s1b += w1v[j] * bfu2f(r1[8192 + t]);
        s2b += w2v[j] * bfu2f(r2[8192 + t]);
      }
    }
    x0a[i] = s0a; x0b[i] = s0b;
    vpa[i] = s2a * s1a; vpb[i] = s2b * s1b;
    buf[SW(n)] = make_float2(vpa[i], vpb[i]);
  }
#pragma unroll
  for (int i = 16; i < 32; ++i) buf[SW(tid + i * 512)] = make_float2(0.f, 0.f);
  __syncthreads();
  dif_fft<512>(buf, tid);
#pragma unroll
  for (int i = 0; i < 32; ++i) {
    const int n = tid + i * 512;
    const float2 a = buf[n], b = kf[i];
    buf[n] = make_float2(a.x * b.x - a.y * b.y, -(a.x * b.y + a.y * b.x));
  }
  __syncthreads();
  dit_fft<512>(buf, tid);
  const float cb  = conv_bias[c];
  const float inv = 1.0f / 16384.0f;
  unsigned short* za = z + (size_t)c * 8192;
  unsigned short* zb = z + (size_t)(1536 + c) * 8192;
#pragma unroll
  for (int i = 0; i < 16; ++i) {
    const int n = tid + i * 512;
    const float2 F = buf[SW(n)];
    za[n] = f2bf((F.x * inv + vpa[i] * cb) * x0a[i]);
    zb[n] = f2bf((-F.y * inv + vpb[i] * cb) * x0b[i]);
  }
}

// ---------------- transpose z[3072][8192] -> zt[16384][1536] ----------------
__global__ __launch_bounds__(256)
void transpose_z(const unsigned short* __restrict__ z, unsigned short* __restrict__ zt) {
  __shared__ unsigned short tile[64][65];
  const int tid = threadIdx.x;
  const int ct = blockIdx.x;
  const int tt = blockIdx.y;
  const int b  = blockIdx.z;
#pragma unroll
  for (int p = 0; p < 2; ++p) {
    const int idx = p * 256 + tid;
    const int row = idx >> 3;
    const int c8  = idx & 7;
    const uint4 v = *(const uint4*)(z + (size_t)(b * 1536 + ct * 64 + row) * 8192 + tt * 64 + c8 * 8);
    unsigned short* tp = &tile[row][c8 * 8];
    tp[0] = (unsigned short)(v.x & 0xffff); tp[1] = (unsigned short)(v.x >> 16);
    tp[2] = (unsigned short)(v.y & 0xffff); tp[3] = (unsigned short)(v.y >> 16);
    tp[4] = (unsigned short)(v.z & 0xffff); tp[5] = (unsigned short)(v.z >> 16);
    tp[6] = (unsigned short)(v.w & 0xffff); tp[7] = (unsigned short)(v.w >> 16);
  }
  __syncthreads();
#pragma unroll
  for (int p = 0; p < 2; ++p) {
    const int idx  = p * 256 + tid;
    const int trow = idx >> 3;
    const int cc   = idx & 7;
    uint4 o;
    o.x = (unsigned)tile[cc * 8 + 0][trow] | ((unsigned)tile[cc * 8 + 1][trow] << 16);
    o.y = (unsigned)tile[cc * 8 + 2][trow] | ((unsigned)tile[cc * 8 + 3][trow] << 16);
    o.z = (unsigned)tile[cc * 8 + 4][trow] | ((unsigned)tile[cc * 8 + 5][trow] << 16);
    o.w = (unsigned)tile[cc * 8 + 6][trow] | ((unsigned)tile[cc * 8 + 7][trow] << 16);
    *(uint4*)(zt + (size_t)(b * 8192 + tt * 64 + trow) * 1536 + ct * 64 + cc * 8) = o;
  }
}

// ---------------------------------------------------------------------------
extern "C" void kernel_launch(void* const* d_in, const int* in_sizes, int n_in,
                              void* d_out, int out_size, void* d_ws, size_t ws_size,
                              hipStream_t stream) {
  const float* u   = (const float*)d_in[0];
  const float* w1  = (const float*)d_in[1];
  const float* b1  = (const float*)d_in[2];
  const float* sw  = (const float*)d_in[3];
  const float* sb  = (const float*)d_in[4];
  const float* km  = (const float*)d_in[5];
  const float* cb  = (const float*)d_in[6];
  const float* w2  = (const float*)d_in[7];
  const float* b2  = (const float*)d_in[8];
  float* outp = (float*)d_out;

  char* ws = (char*)d_ws;
  constexpr size_t OFF_UBF  = 0;
  constexpr size_t OFF_W1   = 25165824;
  constexpr size_t OFF_W2   = 26935296;
  constexpr size_t OFF_UPT  = 29294592;
  constexpr size_t OFF_ZBUF = 67043328;
  constexpr size_t OFF_KF   = 117374976;   // P,Q tables; ztb aliases (dead by then)
  constexpr size_t OFF_ZTB  = 117374976;
  constexpr size_t KF_SZ    = 100663296;   // 1536*8192*8 B
  constexpr size_t OFF_TW   = OFF_KF + KF_SZ;   // 218038272
  constexpr size_t TW_SZ    = 65536;

  unsigned short* u_bf  = (unsigned short*)(ws + OFF_UBF);
  unsigned short* w1_bf = (unsigned short*)(ws + OFF_W1);
  unsigned short* w2_bf = (unsigned short*)(ws + OFF_W2);
  unsigned short* upT   = (unsigned short*)(ws + OFF_UPT);
  unsigned short* zbuf  = (unsigned short*)(ws + OFF_ZBUF);
  uint2*          kfbuf = (uint2*)(ws + OFF_KF);
  float2*         twbuf = (float2*)(ws + OFF_TW);
  unsigned short* ztb   = (unsigned short*)(ws + OFF_ZTB);

  cast_f32_to_bf16<<<12288, 256, 0, stream>>>(u,  u_bf,  12582912);
  cast_f32_to_bf16<<<  864, 256, 0, stream>>>(w1, w1_bf,   884736);
  cast_f32_to_bf16<<< 1152, 256, 0, stream>>>(w2, w2_bf,  1179648);

  dim3 g1(128, 9);
  gemm_bt<1><<<g1, 256, 0, stream>>>(u_bf, w1_bf, b1, upT, 16384, 1152, 768);

  if (ws_size >= OFF_TW + TW_SZ) {
    tw_init_kernel<<<16, 512, 0, stream>>>(twbuf);
    fft_k_kernel<<<1536, 512, 0, stream>>>(km, cb, kfbuf, twbuf);
    hyena_fftconv_split<<<dim3(2, 1536), 512, 0, stream>>>(upT, kfbuf, sw, sb, twbuf, zbuf);
  } else {
    hyena_fftconv_mono<<<1536, 512, 0, stream>>>(upT, km, sw, sb, cb, zbuf);
  }

  transpose_z<<<dim3(24, 128, 2), 256, 0, stream>>>(zbuf, ztb);

  dim3 g2(128, 6);
  gemm_bt<0><<<g2, 256, 0, stream>>>(ztb, w2_bf, b2, outp, 16384, 768, 1536);
}

// Round 10
// 358.671 us; speedup vs baseline: 1.0245x; 1.0245x over previous
//
#include <hip/hip_runtime.h>
#include <cstdint>
#include <cstddef>

// ---------------------------------------------------------------------------
// Hyena operator, MI355X.
//  cast(u,W1,W2)->bf16 ; GEMM1 (bf16 MFMA, writes upT[1152][16384] bf16 +bias)
//  tw_init: twiddle tables (64 KB global, L2-resident, shared by all blocks).
//  fft_k: per channel, 8192-pt complex FFT of even/odd-packed real kernel;
//         Hermitian-split -> P,Q tables (fp16, slot order) incl. conv_bias.
//  fftconv_split: per (batch,channel): pack z[m]=v[2m]+i*v[2m+1] (depthwise
//         conv3 + pre-gate fused, scaled 1/8192) -> 3 radix-16 DIF trips ->
//         fused [radix2-fwd -> T = Z*P + conj(Zpair)*Q -> radix2-inv] ->
//         3 radix-16 DIT trips -> finalize (post-gate x0) -> z bf16. 64 KB LDS.
//  transpose z -> zt ; GEMM2 (bf16 MFMA, f32 out+bias) -> d_out
// Addressing discipline (r10): swizzled LDS addresses decompose as
//   addr_k = sbase XOR XC[k]  (sbase once/trip, XC[k] compile-time)
// so each access is 1 v_xor (or a pure ds offset-immediate for stride-512
// trips) instead of recomputing the swizzle (~5 VALU) per access.
// Register discipline (hard-won): 512 threads/block, NO waves_per_eu and NO
// 1024-thread blocks — both force a 64-VGPR budget -> ~260 MB scratch spills
// (proven rounds 2/4/5/7).
// ---------------------------------------------------------------------------

using s16x8 = __attribute__((ext_vector_type(8))) short;
using f32x4 = __attribute__((ext_vector_type(4))) float;

__device__ __forceinline__ float bfu2f(unsigned short h) {
  union { unsigned int u; float f; } a; a.u = ((unsigned int)h) << 16; return a.f;
}
__device__ __forceinline__ unsigned short f2bf(float f) {
  union { float f; unsigned int u; } a; a.f = f;
  unsigned int r = a.u + 0x7fffu + ((a.u >> 16) & 1u);
  return (unsigned short)(r >> 16);
}
__device__ __forceinline__ unsigned f2h2(float x, float y) {
  union { _Float16 h[2]; unsigned u; } v;
  v.h[0] = (_Float16)x; v.h[1] = (_Float16)y; return v.u;
}
__device__ __forceinline__ float2 h2f2(unsigned u) {
  union { unsigned u; _Float16 h[2]; } v; v.u = u;
  return make_float2((float)v.h[0], (float)v.h[1]);
}
__device__ __forceinline__ float2 cmul(float2 a, float2 b) {
  return make_float2(a.x*b.x - a.y*b.y, a.x*b.y + a.y*b.x);
}
// a * conj(w)
__device__ __forceinline__ float2 cmulcj(float2 a, float2 w) {
  return make_float2(a.x*w.x + a.y*w.y, a.y*w.x - a.x*w.y);
}
__device__ __forceinline__ float2 cmulc(float2 a, float cr, float ci) {
  return make_float2(a.x*cr - a.y*ci, a.x*ci + a.y*cr);
}
__device__ __forceinline__ float2 cadd(float2 a, float2 b) { return make_float2(a.x+b.x, a.y+b.y); }
__device__ __forceinline__ float2 csub(float2 a, float2 b) { return make_float2(a.x-b.x, a.y-b.y); }
__device__ __forceinline__ float2 conjf(float2 a) { return make_float2(a.x, -a.y); }
// LDS bank swizzle at float2 granularity (involution, bits 4..7 preserved).
__device__ __forceinline__ int SW(int p) { return p ^ ((p >> 4) & 15); }
// byte-space LDS accessors (addr precomputed; 1 xor or imm-offset per access)
__device__ __forceinline__ float2 lds_ld(const float2* b, int byteoff) {
  return *(const float2*)((const char*)b + byteoff);
}
__device__ __forceinline__ void lds_st(float2* b, int byteoff, float2 v) {
  *(float2*)((char*)b + byteoff) = v;
}
// 3-nibble reverse: slot<->frequency map for the [16,16,16,2] digit-reversed
// DIF layout (slot 2t holds freq nibrev3(t)).
__device__ __forceinline__ int nibrev3(int x) {
  return ((x & 15) << 8) | (x & 0xF0) | ((x >> 8) & 15);
}

#define TWOPI 6.2831853071795864769f
// twiddle table offsets (float2 units): TA 15x512, TB 15x32, TC 15x2
#define TWB_OFF 7680
#define TWC_OFF 8160
#define TW_TOTAL 8190

// ---------------- twiddle table init (runs once, 64 KB) ----------------
__global__ __launch_bounds__(512)
void tw_init_kernel(float2* __restrict__ tw) {
  const int i = blockIdx.x * 512 + threadIdx.x;
  float sn = 0.f, cs = 1.f;
  if (i < TWB_OFF) {                    // TA: W_8192^(k*j), k=1..15, j=0..511
    const int k = (i >> 9) + 1, j = i & 511;
    sincosf(-TWOPI * (float)(k * j) / 8192.0f, &sn, &cs);
    tw[i] = make_float2(cs, sn);
  } else if (i < TWC_OFF) {             // TB: W_512^(k*j), j=0..31
    const int b = i - TWB_OFF;
    const int k = (b >> 5) + 1, j = b & 31;
    sincosf(-TWOPI * (float)(k * j) / 512.0f, &sn, &cs);
    tw[i] = make_float2(cs, sn);
  } else if (i < TW_TOTAL) {            // TC: W_32^(k*j), j=0..1
    const int b = i - TWC_OFF;
    const int k = (b >> 1) + 1, j = b & 1;
    sincosf(-TWOPI * (float)(k * j) / 32.0f, &sn, &cs);
    tw[i] = make_float2(cs, sn);
  }
}

// ---------------- cast f32 -> bf16 ----------------
__global__ __launch_bounds__(256)
void cast_f32_to_bf16(const float* __restrict__ src, unsigned short* __restrict__ dst, const int n) {
  const int i = (blockIdx.x * 256 + threadIdx.x) * 4;
  if (i < n) {
    const float4 v = *(const float4*)(src + i);
    ushort4 o;
    o.x = f2bf(v.x); o.y = f2bf(v.y); o.z = f2bf(v.z); o.w = f2bf(v.w);
    *(ushort4*)(dst + i) = o;
  }
}

// ---------------- bf16 GEMM: C[m][n] = sum_k A[m][k]*B[n][k] + bias[n] ------
template<int TRANS>
__global__ __launch_bounds__(256)
void gemm_bt(const unsigned short* __restrict__ A, const unsigned short* __restrict__ B,
             const float* __restrict__ bias, void* __restrict__ Cout,
             const int M, const int N, const int K) {
  __shared__ unsigned short As[128 * 32];
  __shared__ unsigned short Bs[128 * 32];
  const int tid  = threadIdx.x;
  const int lane = tid & 63;
  const int wave = tid >> 6;
  const int m0 = blockIdx.x * 128;
  const int n0 = blockIdx.y * 128;
  const int wm = (wave >> 1) * 64;
  const int wn = (wave & 1) * 64;
  f32x4 acc[4][4] = {};

  const int srow = lane >> 2;
  const int scol = (lane & 3) * 8;

  for (int k0 = 0; k0 < K; k0 += 32) {
    __syncthreads();
#pragma unroll
    for (int pass = 0; pass < 2; ++pass) {
      const int rbase = pass * 64 + wave * 16;
      const unsigned short* ga = A + (size_t)(m0 + rbase + srow) * K + k0 + scol;
      const unsigned short* gb = B + (size_t)(n0 + rbase + srow) * K + k0 + scol;
      __builtin_amdgcn_global_load_lds((__attribute__((address_space(1))) void*)ga,
                                       (__attribute__((address_space(3))) void*)(As + rbase * 32), 16, 0, 0);
      __builtin_amdgcn_global_load_lds((__attribute__((address_space(1))) void*)gb,
                                       (__attribute__((address_space(3))) void*)(Bs + rbase * 32), 16, 0, 0);
    }
    __syncthreads();
    s16x8 af[4], bfr[4];
#pragma unroll
    for (int i = 0; i < 4; ++i) {
      af[i]  = *(const s16x8*)(As + (wm + i * 16 + (lane & 15)) * 32 + (lane >> 4) * 8);
      bfr[i] = *(const s16x8*)(Bs + (wn + i * 16 + (lane & 15)) * 32 + (lane >> 4) * 8);
    }
#pragma unroll
    for (int mi = 0; mi < 4; ++mi)
#pragma unroll
      for (int ni = 0; ni < 4; ++ni)
        acc[mi][ni] = __builtin_amdgcn_mfma_f32_16x16x32_bf16(af[mi], bfr[ni], acc[mi][ni], 0, 0, 0);
  }
#pragma unroll
  for (int mi = 0; mi < 4; ++mi) {
#pragma unroll
    for (int ni = 0; ni < 4; ++ni) {
      const int col  = n0 + wn + ni * 16 + (lane & 15);
      const int row0 = m0 + wm + mi * 16 + (lane >> 4) * 4;
      const float bv = bias[col];
      if (TRANS) {
        unsigned short* Ct = (unsigned short*)Cout;
        ushort4 o;
        o.x = f2bf(acc[mi][ni][0] + bv);
        o.y = f2bf(acc[mi][ni][1] + bv);
        o.z = f2bf(acc[mi][ni][2] + bv);
        o.w = f2bf(acc[mi][ni][3] + bv);
        *(ushort4*)(Ct + (size_t)col * M + row0) = o;
      } else {
        float* C = (float*)Cout;
#pragma unroll
        for (int rr = 0; rr < 4; ++rr)
          C[(size_t)(row0 + rr) * N + col] = acc[mi][ni][rr] + bv;
      }
    }
  }
}

// =================== radix-16 FFT building blocks ===========================
template<int SGN>   // -1: fwd, +1: inv
__device__ __forceinline__ void dft4(float2& a, float2& b, float2& c, float2& d) {
  const float2 t0 = cadd(a, c), t1 = csub(a, c);
  const float2 t2 = cadd(b, d), t3 = csub(b, d);
  const float2 jt3 = (SGN < 0) ? make_float2(t3.y, -t3.x) : make_float2(-t3.y, t3.x);
  a = cadd(t0, t2);
  c = csub(t0, t2);
  b = cadd(t1, jt3);
  d = csub(t1, jt3);
}
template<int SGN>
__device__ __forceinline__ void dft4_half(float2& a, float2& b, float2& c, float2& d) {
  const float2 a0 = a, b0 = b;
  const float2 jb = (SGN < 0) ? make_float2(b0.y, -b0.x) : make_float2(-b0.y, b0.x);
  a = cadd(a0, b0);
  c = csub(a0, b0);
  b = cadd(a0, jb);
  d = csub(a0, jb);
}
template<int SGN>
__device__ __forceinline__ void dft4_lo(float2& a, float2& b, const float2 c, const float2 d) {
  const float2 t0 = cadd(a, c), t1 = csub(a, c);
  const float2 t2 = cadd(b, d), t3 = csub(b, d);
  const float2 jt3 = (SGN < 0) ? make_float2(t3.y, -t3.x) : make_float2(-t3.y, t3.x);
  a = cadd(t0, t2);
  b = cadd(t1, jt3);
}

// 16-point DFT, 4x4 decomposition. Input x_m at y[m]; output X[k] is read
// back via y[4*(k&3) + (k>>2)] (digit swap undone by callers).
template<int SGN, bool HALFIN, bool LO8>
__device__ __forceinline__ void dft16_core(float2* y) {
#pragma unroll
  for (int m0 = 0; m0 < 4; ++m0) {
    if (HALFIN) dft4_half<SGN>(y[m0], y[4+m0], y[8+m0], y[12+m0]);
    else        dft4<SGN>(y[m0], y[4+m0], y[8+m0], y[12+m0]);
  }
  const float sg = (SGN < 0) ? -1.f : 1.f;
  const float C_ = 0.92387953251128675613f;
  const float S_ = 0.38268343236508977173f;
  const float R_ = 0.70710678118654752440f;
  y[5]  = cmulc(y[5],  C_,  sg*S_);
  y[6]  = cmulc(y[6],  R_,  sg*R_);
  y[7]  = cmulc(y[7],  S_,  sg*C_);
  y[9]  = cmulc(y[9],  R_,  sg*R_);
  y[10] = (SGN < 0) ? make_float2(y[10].y, -y[10].x) : make_float2(-y[10].y, y[10].x);
  y[11] = cmulc(y[11], -R_, sg*R_);
  y[13] = cmulc(y[13], S_,  sg*C_);
  y[14] = cmulc(y[14], -R_, sg*R_);
  y[15] = cmulc(y[15], -C_, -sg*S_);
#pragma unroll
  for (int k0 = 0; k0 < 4; ++k0) {
    if (LO8) dft4_lo<SGN>(y[4*k0], y[4*k0+1], y[4*k0+2], y[4*k0+3]);
    else     dft4<SGN>(y[4*k0], y[4*k0+1], y[4*k0+2], y[4*k0+3]);
  }
}

// ---- precomputed swizzled addressing (byte space) --------------------------
// Trip B (S=32, M=512):  addr_k = sbaseB ^ XCB(k);  verified vs SW() by hand.
// Trip C (S=2,  M=32):   addr_k = sbaseC ^ XCC(k).
// Trip A/A' (S=512):     addr_k = sbaseA + k*4096 (pure offset immediates).
__device__ __forceinline__ int sbaseA(const int tid) {
  return (tid ^ ((tid >> 4) & 15)) << 3;
}
__device__ __forceinline__ int sbaseB(const int tid) {
  const int j = tid & 31;
  const int base = ((tid >> 5) << 9) | j;
  return (base ^ ((tid >> 4) & 1)) << 3;
}
__device__ __forceinline__ constexpr int XCB(const int k) {
  return (((k << 5) | ((k & 7) << 1)) << 3);
}
__device__ __forceinline__ int sbaseC(const int tid) {
  const int base = ((tid >> 1) << 5) | (tid & 1);
  return (base ^ (((tid >> 1) & 7) << 1)) << 3;
}
__device__ __forceinline__ constexpr int XCC(const int k) {
  return (((k << 1) | (k >> 3)) << 3);
}
// pairing slots 2t, 2t+1: byte addrs spair(t), spair(t)^8
__device__ __forceinline__ int spair(const int t) {
  return ((2 * t) ^ ((t >> 3) & 15)) << 3;
}

// 8192-pt trips, 512 threads, table twiddles (TW layout [k-1][2^LOGS]).
template<int LOGS>
__device__ __forceinline__ void t8_fwd_tw(float2* __restrict__ buf, const int tid,
                                          const float2* __restrict__ TW) {
  const int j  = tid & ((1 << LOGS) - 1);
  const int sb = (LOGS == 5) ? sbaseB(tid) : sbaseC(tid);
  float2 y[16];
#pragma unroll
  for (int m = 0; m < 16; ++m)
    y[m] = lds_ld(buf, sb ^ ((LOGS == 5) ? XCB(m) : XCC(m)));
  dft16_core<-1, false, false>(y);
  lds_st(buf, sb, y[0]);
#pragma unroll
  for (int k = 1; k < 16; ++k)
    lds_st(buf, sb ^ ((LOGS == 5) ? XCB(k) : XCC(k)),
           cmul(y[4*(k&3) + (k>>2)], TW[(k-1)*(1 << LOGS) + j]));
}
template<int LOGS>
__device__ __forceinline__ void t8_inv_tw(float2* __restrict__ buf, const int tid,
                                          const float2* __restrict__ TW) {
  const int j  = tid & ((1 << LOGS) - 1);
  const int sb = (LOGS == 5) ? sbaseB(tid) : sbaseC(tid);
  float2 y[16];
  y[0] = lds_ld(buf, sb);
#pragma unroll
  for (int k = 1; k < 16; ++k)
    y[k] = cmulcj(lds_ld(buf, sb ^ ((LOGS == 5) ? XCB(k) : XCC(k))),
                  TW[(k-1)*(1 << LOGS) + j]);
  dft16_core<1, false, false>(y);
#pragma unroll
  for (int m = 0; m < 16; ++m)
    lds_st(buf, sb ^ ((LOGS == 5) ? XCB(m) : XCC(m)), y[4*(m&3) + (m>>2)]);
}
// trip A fwd (S=512, M=8192), input y[0..7] from regs, upper half zero.
__device__ __forceinline__ void t8_A_fwd_reg_tw(float2* __restrict__ buf, const int tid,
                                                float2* y, const float2* __restrict__ TA) {
  dft16_core<-1, true, false>(y);
  const int sb = sbaseA(tid);
  lds_st(buf, sb, y[0]);
#pragma unroll
  for (int k = 1; k < 16; ++k)
    lds_st(buf, sb + (k << 12), cmul(y[4*(k&3) + (k>>2)], TA[(k-1)*512 + tid]));
}

// ---------------- fft_k: P,Q tables from 8192-pt rfft of kernel -------------
// z[m] = k[2m] + i*k[2m+1] (free pack: raw float2 load). After DIF trips
// (pre-final-radix2), slot pair (2t,2t+1) = freqs (k0, k0+4096), k0=nibrev3(t).
// P(k) = E(k)+cb - s_k*F(k), Q(k) = i*c_k*F(k), F = W16384^k * O(k),
// E=(Z+conj(Zpair))/2, O=(Z-conj(Zpair))/(2i). Stored fp16 at slot index.
__global__ __launch_bounds__(512)
void fft_k_kernel(const float* __restrict__ kmat, const float* __restrict__ conv_bias,
                  uint2* __restrict__ G, const float2* __restrict__ tw) {
  __shared__ float2 buf[8192];                               // 64 KB
  const int tid = threadIdx.x;
  const int c   = blockIdx.x;
  const float* kr = kmat + (size_t)c * 8192;
  {
    float2 y[16];
#pragma unroll
    for (int r = 0; r < 8; ++r) y[r] = *(const float2*)(kr + 2 * (tid + (r << 9)));
    t8_A_fwd_reg_tw(buf, tid, y, tw);
  }
  __syncthreads();
  t8_fwd_tw<5>(buf, tid, tw + TWB_OFF);
  __syncthreads();
  t8_fwd_tw<1>(buf, tid, tw + TWC_OFF);
  __syncthreads();
  const float cb = conv_bias[c];
  uint2* Gt = G + (size_t)c * 8192;
#pragma unroll 1
  for (int i = 0; i < 8; ++i) {
    const int t  = tid + (i << 9);
    const int k0 = nibrev3(t);
    const int st = spair(t);
    const float2 La = lds_ld(buf, st), Lb = lds_ld(buf, st ^ 8);
    const float2 Z0 = cadd(La, Lb), Z1 = csub(La, Lb);   // freqs k0, k0+4096
    float2 Zt0, Zt1;                                      // conj pairs
    if (t == 0) { Zt0 = conjf(Z0); Zt1 = conjf(Z1); }
    else {
      const int tp  = nibrev3((8192 - k0) & 4095);
      const int stp = spair(tp);
      const float2 Lc = lds_ld(buf, stp), Ld = lds_ld(buf, stp ^ 8);
      Zt0 = conjf(csub(Lc, Ld));   // conj(Z[8192-k0])
      Zt1 = conjf(cadd(Lc, Ld));   // conj(Z[4096-k0])
    }
    float sn, cs;
    __sincosf((float)k0 * (TWOPI / 16384.0f), &sn, &cs);
    // freq k0: W = (cs,-sn)
    const float2 E0 = make_float2(0.5f * (Z0.x + Zt0.x), 0.5f * (Z0.y + Zt0.y));
    const float2 d0 = csub(Z0, Zt0);
    const float2 O0 = make_float2(0.5f * d0.y, -0.5f * d0.x);
    const float2 F0 = cmul(make_float2(cs, -sn), O0);
    const float2 P0 = make_float2(E0.x + cb - sn * F0.x, E0.y - sn * F0.y);
    const float2 Q0 = make_float2(-cs * F0.y, cs * F0.x);
    // freq k0+4096: s->cs, c->-sn, W -> (-sn,-cs)
    const float2 E1 = make_float2(0.5f * (Z1.x + Zt1.x), 0.5f * (Z1.y + Zt1.y));
    const float2 d1 = csub(Z1, Zt1);
    const float2 O1 = make_float2(0.5f * d1.y, -0.5f * d1.x);
    const float2 F1 = cmul(make_float2(-sn, -cs), O1);
    const float2 P1 = make_float2(E1.x + cb - cs * F1.x, E1.y - cs * F1.y);
    const float2 Q1 = make_float2(sn * F1.y, -sn * F1.x);
    uint4 o;
    o.x = f2h2(P0.x, P0.y); o.y = f2h2(Q0.x, Q0.y);
    o.z = f2h2(P1.x, P1.y); o.w = f2h2(Q1.x, Q1.y);
    *(uint4*)(Gt + 2 * t) = o;                            // coalesced, linear
  }
}

// ---------------- main fused kernel (per batch x channel) -------------------
__global__ __launch_bounds__(512)
void hyena_fftconv_split(const unsigned short* __restrict__ upT,  // [1152][16384]
                         const uint2* __restrict__ G,              // P,Q fp16
                         const float* __restrict__ short_w,
                         const float* __restrict__ short_b,
                         const float2* __restrict__ tw,
                         unsigned short* __restrict__ z) {          // [3072][8192]
  __shared__ float2 buf[8192];                               // 64 KB
  const int tid = threadIdx.x;
  const int c   = blockIdx.y;
  const int bat = blockIdx.x;

  // ---- pack: depthwise conv3 + pre-gate; z[m] = v[2m] + i*v[2m+1], /8192 ---
  const int c0 = c % 1152;
  const int c1 = (c + 384) % 1152;
  const int c2 = (c + 768) % 1152;
  const unsigned short* r0 = upT + (size_t)c0 * 16384 + bat * 8192;
  const unsigned short* r1 = upT + (size_t)c1 * 16384 + bat * 8192;
  const unsigned short* r2 = upT + (size_t)c2 * 16384 + bat * 8192;
  float w0[3], w1v[3], w2v[3];
#pragma unroll
  for (int j = 0; j < 3; ++j) {
    w0[j]  = short_w[(size_t)c * 3 + j];
    w1v[j] = short_w[(size_t)(1536 + c) * 3 + j];
    w2v[j] = short_w[(size_t)(3072 + c) * 3 + j];
  }
  const float b0 = short_b[c], b1s = short_b[1536 + c], b2s = short_b[3072 + c];
  const float s = 1.0f / 8192.0f;
  float2 xy[8];
  unsigned x0p[8];   // packed bf16 post-gates (lo=even sample, hi=odd)
#pragma unroll
  for (int r = 0; r < 8; ++r) {
    const int m = tid + (r << 9);           // m < 4096
    const unsigned e0 = *(const unsigned*)(r0 + 2 * m);
    const unsigned e1 = *(const unsigned*)(r1 + 2 * m);
    const unsigned e2 = *(const unsigned*)(r2 + 2 * m);
    unsigned p0 = 0, p1 = 0, p2 = 0;
    if (m > 0) {
      p0 = *(const unsigned*)(r0 + 2 * m - 2);
      p1 = *(const unsigned*)(r1 + 2 * m - 2);
      p2 = *(const unsigned*)(r2 + 2 * m - 2);
    }
    const float u0a = bfu2f((unsigned short)(p0 & 0xffff)), u0b = bfu2f((unsigned short)(p0 >> 16));
    const float u0c = bfu2f((unsigned short)(e0 & 0xffff)), u0d = bfu2f((unsigned short)(e0 >> 16));
    const float u1a = bfu2f((unsigned short)(p1 & 0xffff)), u1b = bfu2f((unsigned short)(p1 >> 16));
    const float u1c = bfu2f((unsigned short)(e1 & 0xffff)), u1d = bfu2f((unsigned short)(e1 >> 16));
    const float u2a = bfu2f((unsigned short)(p2 & 0xffff)), u2b = bfu2f((unsigned short)(p2 >> 16));
    const float u2c = bfu2f((unsigned short)(e2 & 0xffff)), u2d = bfu2f((unsigned short)(e2 >> 16));
    const float x0e = b0  + w0[0]  * u0a + w0[1]  * u0b + w0[2]  * u0c;
    const float x0o = b0  + w0[0]  * u0b + w0[1]  * u0c + w0[2]  * u0d;
    const float x1e = b1s + w1v[0] * u1a + w1v[1] * u1b + w1v[2] * u1c;
    const float x1o = b1s + w1v[0] * u1b + w1v[1] * u1c + w1v[2] * u1d;
    const float vE  = b2s + w2v[0] * u2a + w2v[1] * u2b + w2v[2] * u2c;
    const float vO  = b2s + w2v[0] * u2b + w2v[1] * u2c + w2v[2] * u2d;
    xy[r] = make_float2(vE * x1e * s, vO * x1o * s);
    x0p[r] = (unsigned)f2bf(x0e) | ((unsigned)f2bf(x0o) << 16);
  }

  // ---- forward: trip A (regs, half-zero) + trips B, C ----
  {
    float2 y[16];
#pragma unroll
    for (int r = 0; r < 8; ++r) y[r] = xy[r];
    t8_A_fwd_reg_tw(buf, tid, y, tw);
  }
  __syncthreads();
  t8_fwd_tw<5>(buf, tid, tw + TWB_OFF);
  __syncthreads();
  t8_fwd_tw<1>(buf, tid, tw + TWC_OFF);
  __syncthreads();

  // ---- fused: radix2-fwd -> T = Z*P + conj(Zpair)*Q -> radix2-inv ----
  // Quads {2t,2t+1,2t',2t'+1} are disjoint; canonical owner (t <= t') writes.
  const uint2* Gt = G + (size_t)c * 8192;
#pragma unroll 1
  for (int i = 0; i < 8; ++i) {
    const int t  = tid + (i << 9);
    const int k0 = nibrev3(t);
    const int st = spair(t);
    const float2 La = lds_ld(buf, st), Lb = lds_ld(buf, st ^ 8);
    const float2 Z0 = cadd(La, Lb), Z1 = csub(La, Lb);   // freqs k0, k0+4096
    if (t == 0) {
      const uint4 g = *(const uint4*)(Gt);
      const float2 T0 = cadd(cmul(Z0, h2f2(g.x)), cmul(conjf(Z0), h2f2(g.y)));
      const float2 T1 = cadd(cmul(Z1, h2f2(g.z)), cmul(conjf(Z1), h2f2(g.w)));
      lds_st(buf, 0, cadd(T0, T1));
      lds_st(buf, 8, csub(T0, T1));
      continue;
    }
    const int tp = nibrev3((8192 - k0) & 4095);
    if (tp < t) continue;
    const int stp = spair(tp);
    const float2 Lc = lds_ld(buf, stp), Ld = lds_ld(buf, stp ^ 8);
    const float2 Z0p = cadd(Lc, Ld), Z1p = csub(Lc, Ld); // freqs 4096-k0, 8192-k0
    const uint4 ga = *(const uint4*)(Gt + 2 * t);        // P,Q at k0, k0+4096
    const uint4 gb = *(const uint4*)(Gt + 2 * tp);       // P,Q at 4096-k0, 8192-k0
    const float2 T0  = cadd(cmul(Z0,  h2f2(ga.x)), cmul(conjf(Z1p), h2f2(ga.y)));
    const float2 T1  = cadd(cmul(Z1,  h2f2(ga.z)), cmul(conjf(Z0p), h2f2(ga.w)));
    const float2 T0p = cadd(cmul(Z0p, h2f2(gb.x)), cmul(conjf(Z1),  h2f2(gb.y)));
    const float2 T1p = cadd(cmul(Z1p, h2f2(gb.z)), cmul(conjf(Z0),  h2f2(gb.w)));
    lds_st(buf, st,      cadd(T0, T1));
    lds_st(buf, st ^ 8,  csub(T0, T1));
    lds_st(buf, stp,     cadd(T0p, T1p));
    lds_st(buf, stp ^ 8, csub(T0p, T1p));
  }
  __syncthreads();

  // ---- inverse: trips C', B', then A' (regs, only m<4096 needed) ----
  t8_inv_tw<1>(buf, tid, tw + TWC_OFF);
  __syncthreads();
  t8_inv_tw<5>(buf, tid, tw + TWB_OFF);
  __syncthreads();
  {
    const int sb = sbaseA(tid);
    float2 y[16];
    y[0] = lds_ld(buf, sb);
#pragma unroll
    for (int k = 1; k < 16; ++k)
      y[k] = cmulcj(lds_ld(buf, sb + (k << 12)), tw[(k-1)*512 + tid]);
    dft16_core<1, false, true>(y);
    unsigned short* za = z + (size_t)(bat * 1536 + c) * 8192;
#pragma unroll
    for (int r = 0; r < 8; ++r) {
      const int m = tid + (r << 9);
      const float2 F = y[4 * (r & 3) + (r >> 2)];       // t[m]: Re=y[2m], Im=y[2m+1]
      const float ga = bfu2f((unsigned short)(x0p[r] & 0xffff));
      const float gb = bfu2f((unsigned short)(x0p[r] >> 16));
      const unsigned o = (unsigned)f2bf(F.x * ga) | ((unsigned)f2bf(F.y * gb) << 16);
      *(unsigned*)(za + 2 * m) = o;
    }
  }
}

// =============== legacy radix-4 monolithic fallback (small ws) ==============
__device__ __forceinline__ void dif_bfly(float2* __restrict__ buf, const int p0, const int q,
                                         const float2 w1, const float2 w2) {
  float2 x0 = buf[SW(p0)];
  float2 x1 = buf[SW(p0 + q)];
  float2 x2 = buf[SW(p0 + 2 * q)];
  float2 x3 = buf[SW(p0 + 3 * q)];
  const float2 ta = cadd(x0, x2), tb = csub(x0, x2);
  const float2 ua = cadd(x1, x3), ub = csub(x1, x3);
  const float2 v02 = cmul(tb, w1);
  float2 v13 = cmul(ub, w1);
  v13 = make_float2(v13.y, -v13.x);
  buf[SW(p0)]         = cadd(ta, ua);
  buf[SW(p0 + q)]     = cmul(csub(ta, ua), w2);
  buf[SW(p0 + 2 * q)] = cadd(v02, v13);
  buf[SW(p0 + 3 * q)] = cmul(csub(v02, v13), w2);
}
__device__ __forceinline__ void dit_bfly(float2* __restrict__ buf, const int p0, const int q,
                                         const float2 w1, const float2 w2) {
  float2 x0 = buf[SW(p0)];
  float2 x1 = buf[SW(p0 + q)];
  float2 x2 = buf[SW(p0 + 2 * q)];
  float2 x3 = buf[SW(p0 + 3 * q)];
  const float2 t1 = cmul(x1, w2);
  const float2 y0 = cadd(x0, t1), y1 = csub(x0, t1);
  const float2 t3 = cmul(x3, w2);
  const float2 y2 = cadd(x2, t3), y3 = csub(x2, t3);
  const float2 t  = cmul(y2, w1);
  float2 t4 = cmul(y3, w1);
  t4 = make_float2(t4.y, -t4.x);
  buf[SW(p0)]         = cadd(y0, t);
  buf[SW(p0 + q)]     = cadd(y1, t4);
  buf[SW(p0 + 2 * q)] = csub(y0, t);
  buf[SW(p0 + 3 * q)] = csub(y1, t4);
}
template<int NTHR>
__device__ __forceinline__ void dif_fft(float2* __restrict__ buf, const int tid) {
  constexpr int ITERS = 4096 / NTHR;
  for (int r = 0; r < 7; ++r) {
    const int qs = 12 - 2 * r;
    const int q  = 1 << qs;
    const float angf = -TWOPI / (float)(4 << qs);
    if (q <= NTHR) {
      const int j = tid & (q - 1);
      float sn, cs; __sincosf(angf * (float)j, &sn, &cs);
      const float2 w1 = make_float2(cs, sn);
      const float2 w2 = cmul(w1, w1);
#pragma unroll
      for (int it = 0; it < ITERS; ++it) {
        const int id = tid + it * NTHR;
        const int p0 = ((id >> qs) << (qs + 2)) + j;
        dif_bfly(buf, p0, q, w1, w2);
      }
    } else {
#pragma unroll
      for (int it = 0; it < ITERS; ++it) {
        const int id = tid + it * NTHR;
        const int j  = id & (q - 1);
        const int p0 = ((id >> qs) << (qs + 2)) + j;
        float sn, cs; __sincosf(angf * (float)j, &sn, &cs);
        const float2 w1 = make_float2(cs, sn);
        dif_bfly(buf, p0, q, w1, cmul(w1, w1));
      }
    }
    __syncthreads();
  }
}
template<int NTHR>
__device__ __forceinline__ void dit_fft(float2* __restrict__ buf, const int tid) {
  constexpr int ITERS = 4096 / NTHR;
  for (int r = 0; r < 7; ++r) {
    const int qs = 2 * r;
    const int q  = 1 << qs;
    const float angf = -TWOPI / (float)(4 << qs);
    if (q <= NTHR) {
      const int j = tid & (q - 1);
      float sn, cs; __sincosf(angf * (float)j, &sn, &cs);
      const float2 w1 = make_float2(cs, sn);
      const float2 w2 = cmul(w1, w1);
#pragma unroll
      for (int it = 0; it < ITERS; ++it) {
        const int id = tid + it * NTHR;
        const int p0 = ((id >> qs) << (qs + 2)) + j;
        dit_bfly(buf, p0, q, w1, w2);
      }
    } else {
#pragma unroll
      for (int it = 0; it < ITERS; ++it) {
        const int id = tid + it * NTHR;
        const int j  = id & (q - 1);
        const int p0 = ((id >> qs) << (qs + 2)) + j;
        float sn, cs; __sincosf(angf * (float)j, &sn, &cs);
        const float2 w1 = make_float2(cs, sn);
        dit_bfly(buf, p0, q, w1, cmul(w1, w1));
      }
    }
    __syncthreads();
  }
}
__global__ __launch_bounds__(512)
void hyena_fftconv_mono(const unsigned short* __restrict__ upT,
                        const float* __restrict__ kmat,
                        const float* __restrict__ short_w,
                        const float* __restrict__ short_b,
                        const float* __restrict__ conv_bias,
                        unsigned short* __restrict__ z) {
  __shared__ float2 buf[16384];
  const int tid = threadIdx.x;
  const int c   = blockIdx.x;
  const float* kr = kmat + (size_t)c * 8192;
#pragma unroll
  for (int i = 0; i < 32; ++i) {
    const int n = tid + i * 512;
    float2 v = make_float2(0.f, 0.f);
    if (n < 8192) v.x = kr[n];
    buf[SW(n)] = v;
  }
  __syncthreads();
  dif_fft<512>(buf, tid);
  float2 kf[32];
#pragma unroll
  for (int i = 0; i < 32; ++i) kf[i] = buf[tid + i * 512];
  __syncthreads();
  const int c0 = c % 1152;
  const int c1 = (c + 384) % 1152;
  const int c2 = (c + 768) % 1152;
  const unsigned short* r0 = upT + (size_t)c0 * 16384;
  const unsigned short* r1 = upT + (size_t)c1 * 16384;
  const unsigned short* r2 = upT + (size_t)c2 * 16384;
  float w0[3], w1v[3], w2v[3];
#pragma unroll
  for (int j = 0; j < 3; ++j) {
    w0[j]  = short_w[(size_t)c * 3 + j];
    w1v[j] = short_w[(size_t)(1536 + c) * 3 + j];
    w2v[j] = short_w[(size_t)(3072 + c) * 3 + j];
  }
  const float b0 = short_b[c], b1s = short_b[1536 + c], b2s = short_b[3072 + c];
  float x0a[16], x0b[16], vpa[16], vpb[16];
#pragma unroll
  for (int i = 0; i < 16; ++i) {
    const int n = tid + i * 512;
    float s0a = b0, s1a = b1s, s2a = b2s;
    float s0b = b0, s1b = b1s, s2b = b2s;
#pragma unroll
    for (int j = 0; j < 3; ++j) {
      const int t = n - 2 + j;
      if (t >= 0) {
        s0a += w0[j]  * bfu2f(r0[t]);
        s1a += w1v[j] * bfu2f(r1[t]);
        s2a += w2v[j] * bfu2f(r2[t]);
        s0b += w0[j]  * bfu2f(r0[8192 + t]);
        s1b += w1v[j] * bfu2f(r1[8192 + t]);
        s2b += w2v[j] * bfu2f(r2[8192 + t]);
      }
    }
    x0a[i] = s0a; x0b[i] = s0b;
    vpa[i] = s2a * s1a; vpb[i] = s2b * s1b;
    buf[SW(n)] = make_float2(vpa[i], vpb[i]);
  }
#pragma unroll
  for (int i = 16; i < 32; ++i) buf[SW(tid + i * 512)] = make_float2(0.f, 0.f);
  __syncthreads();
  dif_fft<512>(buf, tid);
#pragma unroll
  for (int i = 0; i < 32; ++i) {
    const int n = tid + i * 512;
    const float2 a = buf[n], b = kf[i];
    buf[n] = make_float2(a.x * b.x - a.y * b.y, -(a.x * b.y + a.y * b.x));
  }
  __syncthreads();
  dit_fft<512>(buf, tid);
  const float cb  = conv_bias[c];
  const float inv = 1.0f / 16384.0f;
  unsigned short* za = z + (size_t)c * 8192;
  unsigned short* zb = z + (size_t)(1536 + c) * 8192;
#pragma unroll
  for (int i = 0; i < 16; ++i) {
    const int n = tid + i * 512;
    const float2 F = buf[SW(n)];
    za[n] = f2bf((F.x * inv + vpa[i] * cb) * x0a[i]);
    zb[n] = f2bf((-F.y * inv + vpb[i] * cb) * x0b[i]);
  }
}

// ---------------- transpose z[3072][8192] -> zt[16384][1536] ----------------
__global__ __launch_bounds__(256)
void transpose_z(const unsigned short* __restrict__ z, unsigned short* __restrict__ zt) {
  __shared__ unsigned short tile[64][65];
  const int tid = threadIdx.x;
  const int ct = blockIdx.x;
  const int tt = blockIdx.y;
  const int b  = blockIdx.z;
#pragma unroll
  for (int p = 0; p < 2; ++p) {
    const int idx = p * 256 + tid;
    const int row = idx >> 3;
    const int c8  = idx & 7;
    const uint4 v = *(const uint4*)(z + (size_t)(b * 1536 + ct * 64 + row) * 8192 + tt * 64 + c8 * 8);
    unsigned short* tp = &tile[row][c8 * 8];
    tp[0] = (unsigned short)(v.x & 0xffff); tp[1] = (unsigned short)(v.x >> 16);
    tp[2] = (unsigned short)(v.y & 0xffff); tp[3] = (unsigned short)(v.y >> 16);
    tp[4] = (unsigned short)(v.z & 0xffff); tp[5] = (unsigned short)(v.z >> 16);
    tp[6] = (unsigned short)(v.w & 0xffff); tp[7] = (unsigned short)(v.w >> 16);
  }
  __syncthreads();
#pragma unroll
  for (int p = 0; p < 2; ++p) {
    const int idx  = p * 256 + tid;
    const int trow = idx >> 3;
    const int cc   = idx & 7;
    uint4 o;
    o.x = (unsigned)tile[cc * 8 + 0][trow] | ((unsigned)tile[cc * 8 + 1][trow] << 16);
    o.y = (unsigned)tile[cc * 8 + 2][trow] | ((unsigned)tile[cc * 8 + 3][trow] << 16);
    o.z = (unsigned)tile[cc * 8 + 4][trow] | ((unsigned)tile[cc * 8 + 5][trow] << 16);
    o.w = (unsigned)tile[cc * 8 + 6][trow] | ((unsigned)tile[cc * 8 + 7][trow] << 16);
    *(uint4*)(zt + (size_t)(b * 8192 + tt * 64 + trow) * 1536 + ct * 64 + cc * 8) = o;
  }
}

// ---------------------------------------------------------------------------
extern "C" void kernel_launch(void* const* d_in, const int* in_sizes, int n_in,
                              void* d_out, int out_size, void* d_ws, size_t ws_size,
                              hipStream_t stream) {
  const float* u   = (const float*)d_in[0];
  const float* w1  = (const float*)d_in[1];
  const float* b1  = (const float*)d_in[2];
  const float* sw  = (const float*)d_in[3];
  const float* sb  = (const float*)d_in[4];
  const float* km  = (const float*)d_in[5];
  const float* cb  = (const float*)d_in[6];
  const float* w2  = (const float*)d_in[7];
  const float* b2  = (const float*)d_in[8];
  float* outp = (float*)d_out;

  char* ws = (char*)d_ws;
  constexpr size_t OFF_UBF  = 0;
  constexpr size_t OFF_W1   = 25165824;
  constexpr size_t OFF_W2   = 26935296;
  constexpr size_t OFF_UPT  = 29294592;
  constexpr size_t OFF_ZBUF = 67043328;
  constexpr size_t OFF_KF   = 117374976;   // P,Q tables; ztb aliases (dead by then)
  constexpr size_t OFF_ZTB  = 117374976;
  constexpr size_t KF_SZ    = 100663296;   // 1536*8192*8 B
  constexpr size_t OFF_TW   = OFF_KF + KF_SZ;   // 218038272
  constexpr size_t TW_SZ    = 65536;

  unsigned short* u_bf  = (unsigned short*)(ws + OFF_UBF);
  unsigned short* w1_bf = (unsigned short*)(ws + OFF_W1);
  unsigned short* w2_bf = (unsigned short*)(ws + OFF_W2);
  unsigned short* upT   = (unsigned short*)(ws + OFF_UPT);
  unsigned short* zbuf  = (unsigned short*)(ws + OFF_ZBUF);
  uint2*          kfbuf = (uint2*)(ws + OFF_KF);
  float2*         twbuf = (float2*)(ws + OFF_TW);
  unsigned short* ztb   = (unsigned short*)(ws + OFF_ZTB);

  cast_f32_to_bf16<<<12288, 256, 0, stream>>>(u,  u_bf,  12582912);
  cast_f32_to_bf16<<<  864, 256, 0, stream>>>(w1, w1_bf,   884736);
  cast_f32_to_bf16<<< 1152, 256, 0, stream>>>(w2, w2_bf,  1179648);

  dim3 g1(128, 9);
  gemm_bt<1><<<g1, 256, 0, stream>>>(u_bf, w1_bf, b1, upT, 16384, 1152, 768);

  if (ws_size >= OFF_TW + TW_SZ) {
    tw_init_kernel<<<16, 512, 0, stream>>>(twbuf);
    fft_k_kernel<<<1536, 512, 0, stream>>>(km, cb, kfbuf, twbuf);
    hyena_fftconv_split<<<dim3(2, 1536), 512, 0, stream>>>(upT, kfbuf, sw, sb, twbuf, zbuf);
  } else {
    hyena_fftconv_mono<<<1536, 512, 0, stream>>>(upT, km, sw, sb, cb, zbuf);
  }

  transpose_z<<<dim3(24, 128, 2), 256, 0, stream>>>(zbuf, ztb);

  dim3 g2(128, 6);
  gemm_bt<0><<<g2, 256, 0, stream>>>(ztb, w2_bf, b2, outp, 16384, 768, 1536);
}

// Round 11
// 345.991 us; speedup vs baseline: 1.0620x; 1.0366x over previous
//
#include <hip/hip_runtime.h>
#include <cstdint>
#include <cstddef>

// ---------------------------------------------------------------------------
// Hyena operator, MI355X.
//  cast(u,W1,W2)->bf16 ; GEMM1 (bf16 MFMA, writes upT[1152][16384] bf16 +bias)
//  tw_init: twiddle tables (64 KB global, L2-resident, shared by all blocks).
//  fft_k: per channel, 8192-pt complex FFT of even/odd-packed real kernel;
//         Hermitian-split -> P,Q tables (fp16, slot order) incl. conv_bias.
//  fftconv_split: per (batch,channel): pack z[m]=v[2m]+i*v[2m+1] (depthwise
//         conv3 + pre-gate fused, scaled 1/8192) -> 3 radix-16 DIF trips ->
//         fused [radix2-fwd -> T = Z*P + conj(Zpair)*Q -> radix2-inv] ->
//         3 radix-16 DIT trips -> finalize (post-gate x0 RECOMPUTED from upT,
//         not kept in regs) -> z bf16. 64 KB LDS.
//  transpose z -> zt ; GEMM2 (bf16 MFMA, f32 out+bias) -> d_out
// Occupancy discipline (r11): the HW co-resides a 2nd 512-thread block only
// when VGPR <= 64 (r7: 64->2 blocks; r8/r10: 76-84 -> 1 block). The split
// kernel's persistent arrays (xy[8], x0p[8] = 24 VGPRs) are eliminated
// (pack fused into trip A; gate recomputed at finalize) so the
// waves_per_eu(4) cap (VGPR=64) holds WITHOUT the r7 spill catastrophe.
// Spill tripwire: WRITE_SIZE must stay exactly 49152 KB.
// ---------------------------------------------------------------------------

using s16x8 = __attribute__((ext_vector_type(8))) short;
using f32x4 = __attribute__((ext_vector_type(4))) float;

__device__ __forceinline__ float bfu2f(unsigned short h) {
  union { unsigned int u; float f; } a; a.u = ((unsigned int)h) << 16; return a.f;
}
__device__ __forceinline__ unsigned short f2bf(float f) {
  union { float f; unsigned int u; } a; a.f = f;
  unsigned int r = a.u + 0x7fffu + ((a.u >> 16) & 1u);
  return (unsigned short)(r >> 16);
}
__device__ __forceinline__ unsigned f2h2(float x, float y) {
  union { _Float16 h[2]; unsigned u; } v;
  v.h[0] = (_Float16)x; v.h[1] = (_Float16)y; return v.u;
}
__device__ __forceinline__ float2 h2f2(unsigned u) {
  union { unsigned u; _Float16 h[2]; } v; v.u = u;
  return make_float2((float)v.h[0], (float)v.h[1]);
}
__device__ __forceinline__ float2 cmul(float2 a, float2 b) {
  return make_float2(a.x*b.x - a.y*b.y, a.x*b.y + a.y*b.x);
}
// a * conj(w)
__device__ __forceinline__ float2 cmulcj(float2 a, float2 w) {
  return make_float2(a.x*w.x + a.y*w.y, a.y*w.x - a.x*w.y);
}
__device__ __forceinline__ float2 cmulc(float2 a, float cr, float ci) {
  return make_float2(a.x*cr - a.y*ci, a.x*ci + a.y*cr);
}
__device__ __forceinline__ float2 cadd(float2 a, float2 b) { return make_float2(a.x+b.x, a.y+b.y); }
__device__ __forceinline__ float2 csub(float2 a, float2 b) { return make_float2(a.x-b.x, a.y-b.y); }
__device__ __forceinline__ float2 conjf(float2 a) { return make_float2(a.x, -a.y); }
// LDS bank swizzle at float2 granularity (involution, bits 4..7 preserved).
__device__ __forceinline__ int SW(int p) { return p ^ ((p >> 4) & 15); }
// byte-space LDS accessors (addr precomputed; 1 xor or imm-offset per access)
__device__ __forceinline__ float2 lds_ld(const float2* b, int byteoff) {
  return *(const float2*)((const char*)b + byteoff);
}
__device__ __forceinline__ void lds_st(float2* b, int byteoff, float2 v) {
  *(float2*)((char*)b + byteoff) = v;
}
// 3-nibble reverse: slot<->frequency map for the [16,16,16,2] digit-reversed
// DIF layout (slot 2t holds freq nibrev3(t)).
__device__ __forceinline__ int nibrev3(int x) {
  return ((x & 15) << 8) | (x & 0xF0) | ((x >> 8) & 15);
}

#define TWOPI 6.2831853071795864769f
// twiddle table offsets (float2 units): TA 15x512, TB 15x32, TC 15x2
#define TWB_OFF 7680
#define TWC_OFF 8160
#define TW_TOTAL 8190

// ---------------- twiddle table init (runs once, 64 KB) ----------------
__global__ __launch_bounds__(512)
void tw_init_kernel(float2* __restrict__ tw) {
  const int i = blockIdx.x * 512 + threadIdx.x;
  float sn = 0.f, cs = 1.f;
  if (i < TWB_OFF) {                    // TA: W_8192^(k*j), k=1..15, j=0..511
    const int k = (i >> 9) + 1, j = i & 511;
    sincosf(-TWOPI * (float)(k * j) / 8192.0f, &sn, &cs);
    tw[i] = make_float2(cs, sn);
  } else if (i < TWC_OFF) {             // TB: W_512^(k*j), j=0..31
    const int b = i - TWB_OFF;
    const int k = (b >> 5) + 1, j = b & 31;
    sincosf(-TWOPI * (float)(k * j) / 512.0f, &sn, &cs);
    tw[i] = make_float2(cs, sn);
  } else if (i < TW_TOTAL) {            // TC: W_32^(k*j), j=0..1
    const int b = i - TWC_OFF;
    const int k = (b >> 1) + 1, j = b & 1;
    sincosf(-TWOPI * (float)(k * j) / 32.0f, &sn, &cs);
    tw[i] = make_float2(cs, sn);
  }
}

// ---------------- cast f32 -> bf16 ----------------
__global__ __launch_bounds__(256)
void cast_f32_to_bf16(const float* __restrict__ src, unsigned short* __restrict__ dst, const int n) {
  const int i = (blockIdx.x * 256 + threadIdx.x) * 4;
  if (i < n) {
    const float4 v = *(const float4*)(src + i);
    ushort4 o;
    o.x = f2bf(v.x); o.y = f2bf(v.y); o.z = f2bf(v.z); o.w = f2bf(v.w);
    *(ushort4*)(dst + i) = o;
  }
}

// ---------------- bf16 GEMM: C[m][n] = sum_k A[m][k]*B[n][k] + bias[n] ------
template<int TRANS>
__global__ __launch_bounds__(256)
void gemm_bt(const unsigned short* __restrict__ A, const unsigned short* __restrict__ B,
             const float* __restrict__ bias, void* __restrict__ Cout,
             const int M, const int N, const int K) {
  __shared__ unsigned short As[128 * 32];
  __shared__ unsigned short Bs[128 * 32];
  const int tid  = threadIdx.x;
  const int lane = tid & 63;
  const int wave = tid >> 6;
  const int m0 = blockIdx.x * 128;
  const int n0 = blockIdx.y * 128;
  const int wm = (wave >> 1) * 64;
  const int wn = (wave & 1) * 64;
  f32x4 acc[4][4] = {};

  const int srow = lane >> 2;
  const int scol = (lane & 3) * 8;

  for (int k0 = 0; k0 < K; k0 += 32) {
    __syncthreads();
#pragma unroll
    for (int pass = 0; pass < 2; ++pass) {
      const int rbase = pass * 64 + wave * 16;
      const unsigned short* ga = A + (size_t)(m0 + rbase + srow) * K + k0 + scol;
      const unsigned short* gb = B + (size_t)(n0 + rbase + srow) * K + k0 + scol;
      __builtin_amdgcn_global_load_lds((__attribute__((address_space(1))) void*)ga,
                                       (__attribute__((address_space(3))) void*)(As + rbase * 32), 16, 0, 0);
      __builtin_amdgcn_global_load_lds((__attribute__((address_space(1))) void*)gb,
                                       (__attribute__((address_space(3))) void*)(Bs + rbase * 32), 16, 0, 0);
    }
    __syncthreads();
    s16x8 af[4], bfr[4];
#pragma unroll
    for (int i = 0; i < 4; ++i) {
      af[i]  = *(const s16x8*)(As + (wm + i * 16 + (lane & 15)) * 32 + (lane >> 4) * 8);
      bfr[i] = *(const s16x8*)(Bs + (wn + i * 16 + (lane & 15)) * 32 + (lane >> 4) * 8);
    }
#pragma unroll
    for (int mi = 0; mi < 4; ++mi)
#pragma unroll
      for (int ni = 0; ni < 4; ++ni)
        acc[mi][ni] = __builtin_amdgcn_mfma_f32_16x16x32_bf16(af[mi], bfr[ni], acc[mi][ni], 0, 0, 0);
  }
#pragma unroll
  for (int mi = 0; mi < 4; ++mi) {
#pragma unroll
    for (int ni = 0; ni < 4; ++ni) {
      const int col  = n0 + wn + ni * 16 + (lane & 15);
      const int row0 = m0 + wm + mi * 16 + (lane >> 4) * 4;
      const float bv = bias[col];
      if (TRANS) {
        unsigned short* Ct = (unsigned short*)Cout;
        ushort4 o;
        o.x = f2bf(acc[mi][ni][0] + bv);
        o.y = f2bf(acc[mi][ni][1] + bv);
        o.z = f2bf(acc[mi][ni][2] + bv);
        o.w = f2bf(acc[mi][ni][3] + bv);
        *(ushort4*)(Ct + (size_t)col * M + row0) = o;
      } else {
        float* C = (float*)Cout;
#pragma unroll
        for (int rr = 0; rr < 4; ++rr)
          C[(size_t)(row0 + rr) * N + col] = acc[mi][ni][rr] + bv;
      }
    }
  }
}

// =================== radix-16 FFT building blocks ===========================
template<int SGN>   // -1: fwd, +1: inv
__device__ __forceinline__ void dft4(float2& a, float2& b, float2& c, float2& d) {
  const float2 t0 = cadd(a, c), t1 = csub(a, c);
  const float2 t2 = cadd(b, d), t3 = csub(b, d);
  const float2 jt3 = (SGN < 0) ? make_float2(t3.y, -t3.x) : make_float2(-t3.y, t3.x);
  a = cadd(t0, t2);
  c = csub(t0, t2);
  b = cadd(t1, jt3);
  d = csub(t1, jt3);
}
template<int SGN>
__device__ __forceinline__ void dft4_half(float2& a, float2& b, float2& c, float2& d) {
  const float2 a0 = a, b0 = b;
  const float2 jb = (SGN < 0) ? make_float2(b0.y, -b0.x) : make_float2(-b0.y, b0.x);
  a = cadd(a0, b0);
  c = csub(a0, b0);
  b = cadd(a0, jb);
  d = csub(a0, jb);
}
template<int SGN>
__device__ __forceinline__ void dft4_lo(float2& a, float2& b, const float2 c, const float2 d) {
  const float2 t0 = cadd(a, c), t1 = csub(a, c);
  const float2 t2 = cadd(b, d), t3 = csub(b, d);
  const float2 jt3 = (SGN < 0) ? make_float2(t3.y, -t3.x) : make_float2(-t3.y, t3.x);
  a = cadd(t0, t2);
  b = cadd(t1, jt3);
}

// 16-point DFT, 4x4 decomposition. Input x_m at y[m]; output X[k] is read
// back via y[4*(k&3) + (k>>2)] (digit swap undone by callers).
template<int SGN, bool HALFIN, bool LO8>
__device__ __forceinline__ void dft16_core(float2* y) {
#pragma unroll
  for (int m0 = 0; m0 < 4; ++m0) {
    if (HALFIN) dft4_half<SGN>(y[m0], y[4+m0], y[8+m0], y[12+m0]);
    else        dft4<SGN>(y[m0], y[4+m0], y[8+m0], y[12+m0]);
  }
  const float sg = (SGN < 0) ? -1.f : 1.f;
  const float C_ = 0.92387953251128675613f;
  const float S_ = 0.38268343236508977173f;
  const float R_ = 0.70710678118654752440f;
  y[5]  = cmulc(y[5],  C_,  sg*S_);
  y[6]  = cmulc(y[6],  R_,  sg*R_);
  y[7]  = cmulc(y[7],  S_,  sg*C_);
  y[9]  = cmulc(y[9],  R_,  sg*R_);
  y[10] = (SGN < 0) ? make_float2(y[10].y, -y[10].x) : make_float2(-y[10].y, y[10].x);
  y[11] = cmulc(y[11], -R_, sg*R_);
  y[13] = cmulc(y[13], S_,  sg*C_);
  y[14] = cmulc(y[14], -R_, sg*R_);
  y[15] = cmulc(y[15], -C_, -sg*S_);
#pragma unroll
  for (int k0 = 0; k0 < 4; ++k0) {
    if (LO8) dft4_lo<SGN>(y[4*k0], y[4*k0+1], y[4*k0+2], y[4*k0+3]);
    else     dft4<SGN>(y[4*k0], y[4*k0+1], y[4*k0+2], y[4*k0+3]);
  }
}

// ---- precomputed swizzled addressing (byte space) --------------------------
// Trip B (S=32, M=512):  addr_k = sbaseB ^ XCB(k);  verified vs SW() by hand.
// Trip C (S=2,  M=32):   addr_k = sbaseC ^ XCC(k).
// Trip A/A' (S=512):     addr_k = sbaseA + k*4096 (pure offset immediates).
__device__ __forceinline__ int sbaseA(const int tid) {
  return (tid ^ ((tid >> 4) & 15)) << 3;
}
__device__ __forceinline__ int sbaseB(const int tid) {
  const int j = tid & 31;
  const int base = ((tid >> 5) << 9) | j;
  return (base ^ ((tid >> 4) & 1)) << 3;
}
__device__ __forceinline__ constexpr int XCB(const int k) {
  return (((k << 5) | ((k & 7) << 1)) << 3);
}
__device__ __forceinline__ int sbaseC(const int tid) {
  const int base = ((tid >> 1) << 5) | (tid & 1);
  return (base ^ (((tid >> 1) & 7) << 1)) << 3;
}
__device__ __forceinline__ constexpr int XCC(const int k) {
  return (((k << 1) | (k >> 3)) << 3);
}
// pairing slots 2t, 2t+1: byte addrs spair(t), spair(t)^8
__device__ __forceinline__ int spair(const int t) {
  return ((2 * t) ^ ((t >> 3) & 15)) << 3;
}

// 8192-pt trips, 512 threads, table twiddles (TW layout [k-1][2^LOGS]).
template<int LOGS>
__device__ __forceinline__ void t8_fwd_tw(float2* __restrict__ buf, const int tid,
                                          const float2* __restrict__ TW) {
  const int j  = tid & ((1 << LOGS) - 1);
  const int sb = (LOGS == 5) ? sbaseB(tid) : sbaseC(tid);
  float2 y[16];
#pragma unroll
  for (int m = 0; m < 16; ++m)
    y[m] = lds_ld(buf, sb ^ ((LOGS == 5) ? XCB(m) : XCC(m)));
  dft16_core<-1, false, false>(y);
  lds_st(buf, sb, y[0]);
#pragma unroll
  for (int k = 1; k < 16; ++k)
    lds_st(buf, sb ^ ((LOGS == 5) ? XCB(k) : XCC(k)),
           cmul(y[4*(k&3) + (k>>2)], TW[(k-1)*(1 << LOGS) + j]));
}
template<int LOGS>
__device__ __forceinline__ void t8_inv_tw(float2* __restrict__ buf, const int tid,
                                          const float2* __restrict__ TW) {
  const int j  = tid & ((1 << LOGS) - 1);
  const int sb = (LOGS == 5) ? sbaseB(tid) : sbaseC(tid);
  float2 y[16];
  y[0] = lds_ld(buf, sb);
#pragma unroll
  for (int k = 1; k < 16; ++k)
    y[k] = cmulcj(lds_ld(buf, sb ^ ((LOGS == 5) ? XCB(k) : XCC(k))),
                  TW[(k-1)*(1 << LOGS) + j]);
  dft16_core<1, false, false>(y);
#pragma unroll
  for (int m = 0; m < 16; ++m)
    lds_st(buf, sb ^ ((LOGS == 5) ? XCB(m) : XCC(m)), y[4*(m&3) + (m>>2)]);
}
// trip A fwd (S=512, M=8192), input y[0..7] from regs, upper half zero.
__device__ __forceinline__ void t8_A_fwd_reg_tw(float2* __restrict__ buf, const int tid,
                                                float2* y, const float2* __restrict__ TA) {
  dft16_core<-1, true, false>(y);
  const int sb = sbaseA(tid);
  lds_st(buf, sb, y[0]);
#pragma unroll
  for (int k = 1; k < 16; ++k)
    lds_st(buf, sb + (k << 12), cmul(y[4*(k&3) + (k>>2)], TA[(k-1)*512 + tid]));
}

// ---------------- fft_k: P,Q tables from 8192-pt rfft of kernel -------------
// z[m] = k[2m] + i*k[2m+1] (free pack: raw float2 load). After DIF trips
// (pre-final-radix2), slot pair (2t,2t+1) = freqs (k0, k0+4096), k0=nibrev3(t).
// P(k) = E(k)+cb - s_k*F(k), Q(k) = i*c_k*F(k), F = W16384^k * O(k),
// E=(Z+conj(Zpair))/2, O=(Z-conj(Zpair))/(2i). Stored fp16 at slot index.
__global__ __launch_bounds__(512)
void fft_k_kernel(const float* __restrict__ kmat, const float* __restrict__ conv_bias,
                  uint2* __restrict__ G, const float2* __restrict__ tw) {
  __shared__ float2 buf[8192];                               // 64 KB
  const int tid = threadIdx.x;
  const int c   = blockIdx.x;
  const float* kr = kmat + (size_t)c * 8192;
  {
    float2 y[16];
#pragma unroll
    for (int r = 0; r < 8; ++r) y[r] = *(const float2*)(kr + 2 * (tid + (r << 9)));
    t8_A_fwd_reg_tw(buf, tid, y, tw);
  }
  __syncthreads();
  t8_fwd_tw<5>(buf, tid, tw + TWB_OFF);
  __syncthreads();
  t8_fwd_tw<1>(buf, tid, tw + TWC_OFF);
  __syncthreads();
  const float cb = conv_bias[c];
  uint2* Gt = G + (size_t)c * 8192;
#pragma unroll 1
  for (int i = 0; i < 8; ++i) {
    const int t  = tid + (i << 9);
    const int k0 = nibrev3(t);
    const int st = spair(t);
    const float2 La = lds_ld(buf, st), Lb = lds_ld(buf, st ^ 8);
    const float2 Z0 = cadd(La, Lb), Z1 = csub(La, Lb);   // freqs k0, k0+4096
    float2 Zt0, Zt1;                                      // conj pairs
    if (t == 0) { Zt0 = conjf(Z0); Zt1 = conjf(Z1); }
    else {
      const int tp  = nibrev3((8192 - k0) & 4095);
      const int stp = spair(tp);
      const float2 Lc = lds_ld(buf, stp), Ld = lds_ld(buf, stp ^ 8);
      Zt0 = conjf(csub(Lc, Ld));   // conj(Z[8192-k0])
      Zt1 = conjf(cadd(Lc, Ld));   // conj(Z[4096-k0])
    }
    float sn, cs;
    __sincosf((float)k0 * (TWOPI / 16384.0f), &sn, &cs);
    // freq k0: W = (cs,-sn)
    const float2 E0 = make_float2(0.5f * (Z0.x + Zt0.x), 0.5f * (Z0.y + Zt0.y));
    const float2 d0 = csub(Z0, Zt0);
    const float2 O0 = make_float2(0.5f * d0.y, -0.5f * d0.x);
    const float2 F0 = cmul(make_float2(cs, -sn), O0);
    const float2 P0 = make_float2(E0.x + cb - sn * F0.x, E0.y - sn * F0.y);
    const float2 Q0 = make_float2(-cs * F0.y, cs * F0.x);
    // freq k0+4096: s->cs, c->-sn, W -> (-sn,-cs)
    const float2 E1 = make_float2(0.5f * (Z1.x + Zt1.x), 0.5f * (Z1.y + Zt1.y));
    const float2 d1 = csub(Z1, Zt1);
    const float2 O1 = make_float2(0.5f * d1.y, -0.5f * d1.x);
    const float2 F1 = cmul(make_float2(-sn, -cs), O1);
    const float2 P1 = make_float2(E1.x + cb - cs * F1.x, E1.y - cs * F1.y);
    const float2 Q1 = make_float2(sn * F1.y, -sn * F1.x);
    uint4 o;
    o.x = f2h2(P0.x, P0.y); o.y = f2h2(Q0.x, Q0.y);
    o.z = f2h2(P1.x, P1.y); o.w = f2h2(Q1.x, Q1.y);
    *(uint4*)(Gt + 2 * t) = o;                            // coalesced, linear
  }
}

// ---------------- main fused kernel (per batch x channel) -------------------
__attribute__((amdgpu_waves_per_eu(4)))
__global__ __launch_bounds__(512)
void hyena_fftconv_split(const unsigned short* __restrict__ upT,  // [1152][16384]
                         const uint2* __restrict__ G,              // P,Q fp16
                         const float* __restrict__ short_w,
                         const float* __restrict__ short_b,
                         const float2* __restrict__ tw,
                         unsigned short* __restrict__ z) {          // [3072][8192]
  __shared__ float2 buf[8192];                               // 64 KB
  const int tid = threadIdx.x;
  const int c   = blockIdx.y;
  const int bat = blockIdx.x;

  // ---- pack fused into trip A: depthwise conv3 + pre-gate ->
  //      y[r] = (vE*x1e, vO*x1o)/8192 for m = tid + r*512; no persistent
  //      arrays (post-gate x0 is recomputed at finalize from r0).
  const int c0 = c % 1152;
  const int c1 = (c + 384) % 1152;
  const int c2 = (c + 768) % 1152;
  const unsigned short* r0 = upT + (size_t)c0 * 16384 + bat * 8192;
  const unsigned short* r1 = upT + (size_t)c1 * 16384 + bat * 8192;
  const unsigned short* r2 = upT + (size_t)c2 * 16384 + bat * 8192;
  // block-uniform scalars (SGPR-resident)
  const float w00 = short_w[(size_t)c * 3 + 0], w01 = short_w[(size_t)c * 3 + 1],
              w02 = short_w[(size_t)c * 3 + 2];
  const float w10 = short_w[(size_t)(1536 + c) * 3 + 0], w11 = short_w[(size_t)(1536 + c) * 3 + 1],
              w12 = short_w[(size_t)(1536 + c) * 3 + 2];
  const float w20 = short_w[(size_t)(3072 + c) * 3 + 0], w21 = short_w[(size_t)(3072 + c) * 3 + 1],
              w22 = short_w[(size_t)(3072 + c) * 3 + 2];
  const float b0 = short_b[c], b1s = short_b[1536 + c], b2s = short_b[3072 + c];
  const float s = 1.0f / 8192.0f;

  {
    float2 y[16];
#pragma unroll
    for (int r = 0; r < 8; ++r) {
      const int m = tid + (r << 9);           // m < 4096
      const unsigned e1 = *(const unsigned*)(r1 + 2 * m);
      const unsigned e2 = *(const unsigned*)(r2 + 2 * m);
      unsigned p1 = 0, p2 = 0;
      if (m > 0) {
        p1 = *(const unsigned*)(r1 + 2 * m - 2);
        p2 = *(const unsigned*)(r2 + 2 * m - 2);
      }
      const float u1a = bfu2f((unsigned short)(p1 & 0xffff)), u1b = bfu2f((unsigned short)(p1 >> 16));
      const float u1c = bfu2f((unsigned short)(e1 & 0xffff)), u1d = bfu2f((unsigned short)(e1 >> 16));
      const float u2a = bfu2f((unsigned short)(p2 & 0xffff)), u2b = bfu2f((unsigned short)(p2 >> 16));
      const float u2c = bfu2f((unsigned short)(e2 & 0xffff)), u2d = bfu2f((unsigned short)(e2 >> 16));
      const float x1e = b1s + w10 * u1a + w11 * u1b + w12 * u1c;
      const float x1o = b1s + w10 * u1b + w11 * u1c + w12 * u1d;
      const float vE  = b2s + w20 * u2a + w21 * u2b + w22 * u2c;
      const float vO  = b2s + w20 * u2b + w21 * u2c + w22 * u2d;
      y[r] = make_float2(vE * x1e * s, vO * x1o * s);
    }
    t8_A_fwd_reg_tw(buf, tid, y, tw);
  }
  __syncthreads();
  t8_fwd_tw<5>(buf, tid, tw + TWB_OFF);
  __syncthreads();
  t8_fwd_tw<1>(buf, tid, tw + TWC_OFF);
  __syncthreads();

  // ---- fused: radix2-fwd -> T = Z*P + conj(Zpair)*Q -> radix2-inv ----
  // Quads {2t,2t+1,2t',2t'+1} are disjoint; canonical owner (t <= t') writes.
  const uint2* Gt = G + (size_t)c * 8192;
#pragma unroll 1
  for (int i = 0; i < 8; ++i) {
    const int t  = tid + (i << 9);
    const int k0 = nibrev3(t);
    const int st = spair(t);
    const float2 La = lds_ld(buf, st), Lb = lds_ld(buf, st ^ 8);
    const float2 Z0 = cadd(La, Lb), Z1 = csub(La, Lb);   // freqs k0, k0+4096
    if (t == 0) {
      const uint4 g = *(const uint4*)(Gt);
      const float2 T0 = cadd(cmul(Z0, h2f2(g.x)), cmul(conjf(Z0), h2f2(g.y)));
      const float2 T1 = cadd(cmul(Z1, h2f2(g.z)), cmul(conjf(Z1), h2f2(g.w)));
      lds_st(buf, 0, cadd(T0, T1));
      lds_st(buf, 8, csub(T0, T1));
      continue;
    }
    const int tp = nibrev3((8192 - k0) & 4095);
    if (tp < t) continue;
    const int stp = spair(tp);
    const float2 Lc = lds_ld(buf, stp), Ld = lds_ld(buf, stp ^ 8);
    const float2 Z0p = cadd(Lc, Ld), Z1p = csub(Lc, Ld); // freqs 4096-k0, 8192-k0
    const uint4 ga = *(const uint4*)(Gt + 2 * t);        // P,Q at k0, k0+4096
    const uint4 gb = *(const uint4*)(Gt + 2 * tp);       // P,Q at 4096-k0, 8192-k0
    const float2 T0  = cadd(cmul(Z0,  h2f2(ga.x)), cmul(conjf(Z1p), h2f2(ga.y)));
    const float2 T1  = cadd(cmul(Z1,  h2f2(ga.z)), cmul(conjf(Z0p), h2f2(ga.w)));
    const float2 T0p = cadd(cmul(Z0p, h2f2(gb.x)), cmul(conjf(Z1),  h2f2(gb.y)));
    const float2 T1p = cadd(cmul(Z1p, h2f2(gb.z)), cmul(conjf(Z0),  h2f2(gb.w)));
    lds_st(buf, st,      cadd(T0, T1));
    lds_st(buf, st ^ 8,  csub(T0, T1));
    lds_st(buf, stp,     cadd(T0p, T1p));
    lds_st(buf, stp ^ 8, csub(T0p, T1p));
  }
  __syncthreads();

  // ---- inverse: trips C', B', then A' (regs, only m<4096 needed) ----
  t8_inv_tw<1>(buf, tid, tw + TWC_OFF);
  __syncthreads();
  t8_inv_tw<5>(buf, tid, tw + TWB_OFF);
  __syncthreads();
  {
    const int sb = sbaseA(tid);
    float2 y[16];
    y[0] = lds_ld(buf, sb);
#pragma unroll
    for (int k = 1; k < 16; ++k)
      y[k] = cmulcj(lds_ld(buf, sb + (k << 12)), tw[(k-1)*512 + tid]);
    dft16_core<1, false, true>(y);
    // finalize: recompute post-gate x0 from r0 (L2-warm; pack never read r0)
    unsigned short* za = z + (size_t)(bat * 1536 + c) * 8192;
#pragma unroll
    for (int r = 0; r < 8; ++r) {
      const int m = tid + (r << 9);
      const unsigned e0 = *(const unsigned*)(r0 + 2 * m);
      unsigned p0 = 0;
      if (m > 0) p0 = *(const unsigned*)(r0 + 2 * m - 2);
      const float u0a = bfu2f((unsigned short)(p0 & 0xffff)), u0b = bfu2f((unsigned short)(p0 >> 16));
      const float u0c = bfu2f((unsigned short)(e0 & 0xffff)), u0d = bfu2f((unsigned short)(e0 >> 16));
      const float x0e = b0 + w00 * u0a + w01 * u0b + w02 * u0c;
      const float x0o = b0 + w00 * u0b + w01 * u0c + w02 * u0d;
      const float2 F = y[4 * (r & 3) + (r >> 2)];       // t[m]: Re=y[2m], Im=y[2m+1]
      const unsigned o = (unsigned)f2bf(F.x * x0e) | ((unsigned)f2bf(F.y * x0o) << 16);
      *(unsigned*)(za + 2 * m) = o;
    }
  }
}

// =============== legacy radix-4 monolithic fallback (small ws) ==============
__device__ __forceinline__ void dif_bfly(float2* __restrict__ buf, const int p0, const int q,
                                         const float2 w1, const float2 w2) {
  float2 x0 = buf[SW(p0)];
  float2 x1 = buf[SW(p0 + q)];
  float2 x2 = buf[SW(p0 + 2 * q)];
  float2 x3 = buf[SW(p0 + 3 * q)];
  const float2 ta = cadd(x0, x2), tb = csub(x0, x2);
  const float2 ua = cadd(x1, x3), ub = csub(x1, x3);
  const float2 v02 = cmul(tb, w1);
  float2 v13 = cmul(ub, w1);
  v13 = make_float2(v13.y, -v13.x);
  buf[SW(p0)]         = cadd(ta, ua);
  buf[SW(p0 + q)]     = cmul(csub(ta, ua), w2);
  buf[SW(p0 + 2 * q)] = cadd(v02, v13);
  buf[SW(p0 + 3 * q)] = cmul(csub(v02, v13), w2);
}
__device__ __forceinline__ void dit_bfly(float2* __restrict__ buf, const int p0, const int q,
                                         const float2 w1, const float2 w2) {
  float2 x0 = buf[SW(p0)];
  float2 x1 = buf[SW(p0 + q)];
  float2 x2 = buf[SW(p0 + 2 * q)];
  float2 x3 = buf[SW(p0 + 3 * q)];
  const float2 t1 = cmul(x1, w2);
  const float2 y0 = cadd(x0, t1), y1 = csub(x0, t1);
  const float2 t3 = cmul(x3, w2);
  const float2 y2 = cadd(x2, t3), y3 = csub(x2, t3);
  const float2 t  = cmul(y2, w1);
  float2 t4 = cmul(y3, w1);
  t4 = make_float2(t4.y, -t4.x);
  buf[SW(p0)]         = cadd(y0, t);
  buf[SW(p0 + q)]     = cadd(y1, t4);
  buf[SW(p0 + 2 * q)] = csub(y0, t);
  buf[SW(p0 + 3 * q)] = csub(y1, t4);
}
template<int NTHR>
__device__ __forceinline__ void dif_fft(float2* __restrict__ buf, const int tid) {
  constexpr int ITERS = 4096 / NTHR;
  for (int r = 0; r < 7; ++r) {
    const int qs = 12 - 2 * r;
    const int q  = 1 << qs;
    const float angf = -TWOPI / (float)(4 << qs);
    if (q <= NTHR) {
      const int j = tid & (q - 1);
      float sn, cs; __sincosf(angf * (float)j, &sn, &cs);
      const float2 w1 = make_float2(cs, sn);
      const float2 w2 = cmul(w1, w1);
#pragma unroll
      for (int it = 0; it < ITERS; ++it) {
        const int id = tid + it * NTHR;
        const int p0 = ((id >> qs) << (qs + 2)) + j;
        dif_bfly(buf, p0, q, w1, w2);
      }
    } else {
#pragma unroll
      for (int it = 0; it < ITERS; ++it) {
        const int id = tid + it * NTHR;
        const int j  = id & (q - 1);
        const int p0 = ((id >> qs) << (qs + 2)) + j;
        float sn, cs; __sincosf(angf * (float)j, &sn, &cs);
        const float2 w1 = make_float2(cs, sn);
        dif_bfly(buf, p0, q, w1, cmul(w1, w1));
      }
    }
    __syncthreads();
  }
}
template<int NTHR>
__device__ __forceinline__ void dit_fft(float2* __restrict__ buf, const int tid) {
  constexpr int ITERS = 4096 / NTHR;
  for (int r = 0; r < 7; ++r) {
    const int qs = 2 * r;
    const int q  = 1 << qs;
    const float angf = -TWOPI / (float)(4 << qs);
    if (q <= NTHR) {
      const int j = tid & (q - 1);
      float sn, cs; __sincosf(angf * (float)j, &sn, &cs);
      const float2 w1 = make_float2(cs, sn);
      const float2 w2 = cmul(w1, w1);
#pragma unroll
      for (int it = 0; it < ITERS; ++it) {
        const int id = tid + it * NTHR;
        const int p0 = ((id >> qs) << (qs + 2)) + j;
        dit_bfly(buf, p0, q, w1, w2);
      }
    } else {
#pragma unroll
      for (int it = 0; it < ITERS; ++it) {
        const int id = tid + it * NTHR;
        const int j  = id & (q - 1);
        const int p0 = ((id >> qs) << (qs + 2)) + j;
        float sn, cs; __sincosf(angf * (float)j, &sn, &cs);
        const float2 w1 = make_float2(cs, sn);
        dit_bfly(buf, p0, q, w1, cmul(w1, w1));
      }
    }
    __syncthreads();
  }
}
__global__ __launch_bounds__(512)
void hyena_fftconv_mono(const unsigned short* __restrict__ upT,
                        const float* __restrict__ kmat,
                        const float* __restrict__ short_w,
                        const float* __restrict__ short_b,
                        const float* __restrict__ conv_bias,
                        unsigned short* __restrict__ z) {
  __shared__ float2 buf[16384];
  const int tid = threadIdx.x;
  const int c   = blockIdx.x;
  const float* kr = kmat + (size_t)c * 8192;
#pragma unroll
  for (int i = 0; i < 32; ++i) {
    const int n = tid + i * 512;
    float2 v = make_float2(0.f, 0.f);
    if (n < 8192) v.x = kr[n];
    buf[SW(n)] = v;
  }
  __syncthreads();
  dif_fft<512>(buf, tid);
  float2 kf[32];
#pragma unroll
  for (int i = 0; i < 32; ++i) kf[i] = buf[tid + i * 512];
  __syncthreads();
  const int c0 = c % 1152;
  const int c1 = (c + 384) % 1152;
  const int c2 = (c + 768) % 1152;
  const unsigned short* r0 = upT + (size_t)c0 * 16384;
  const unsigned short* r1 = upT + (size_t)c1 * 16384;
  const unsigned short* r2 = upT + (size_t)c2 * 16384;
  float w0[3], w1v[3], w2v[3];
#pragma unroll
  for (int j = 0; j < 3; ++j) {
    w0[j]  = short_w[(size_t)c * 3 + j];
    w1v[j] = short_w[(size_t)(1536 + c) * 3 + j];
    w2v[j] = short_w[(size_t)(3072 + c) * 3 + j];
  }
  const float b0 = short_b[c], b1s = short_b[1536 + c], b2s = short_b[3072 + c];
  float x0a[16], x0b[16], vpa[16], vpb[16];
#pragma unroll
  for (int i = 0; i < 16; ++i) {
    const int n = tid + i * 512;
    float s0a = b0, s1a = b1s, s2a = b2s;
    float s0b = b0, s1b = b1s, s2b = b2s;
#pragma unroll
    for (int j = 0; j < 3; ++j) {
      const int t = n - 2 + j;
      if (t >= 0) {
        s0a += w0[j]  * bfu2f(r0[t]);
        s1a += w1v[j] * bfu2f(r1[t]);
        s2a += w2v[j] * bfu2f(r2[t]);
        s0b += w0[j]  * bfu2f(r0[8192 + t]);
        s1b += w1v[j] * bfu2f(r1[8192 + t]);
        s2b += w2v[j] * bfu2f(r2[8192 + t]);
      }
    }
    x0a[i] = s0a; x0b[i] = s0b;
    vpa[i] = s2a * s1a; vpb[i] = s2b * s1b;
    buf[SW(n)] = make_float2(vpa[i], vpb[i]);
  }
#pragma unroll
  for (int i = 16; i < 32; ++i) buf[SW(tid + i * 512)] = make_float2(0.f, 0.f);
  __syncthreads();
  dif_fft<512>(buf, tid);
#pragma unroll
  for (int i = 0; i < 32; ++i) {
    const int n = tid + i * 512;
    const float2 a = buf[n], b = kf[i];
    buf[n] = make_float2(a.x * b.x - a.y * b.y, -(a.x * b.y + a.y * b.x));
  }
  __syncthreads();
  dit_fft<512>(buf, tid);
  const float cb  = conv_bias[c];
  const float inv = 1.0f / 16384.0f;
  unsigned short* za = z + (size_t)c * 8192;
  unsigned short* zb = z + (size_t)(1536 + c) * 8192;
#pragma unroll
  for (int i = 0; i < 16; ++i) {
    const int n = tid + i * 512;
    const float2 F = buf[SW(n)];
    za[n] = f2bf((F.x * inv + vpa[i] * cb) * x0a[i]);
    zb[n] = f2bf((-F.y * inv + vpb[i] * cb) * x0b[i]);
  }
}

// ---------------- transpose z[3072][8192] -> zt[16384][1536] ----------------
__global__ __launch_bounds__(256)
void transpose_z(const unsigned short* __restrict__ z, unsigned short* __restrict__ zt) {
  __shared__ unsigned short tile[64][65];
  const int tid = threadIdx.x;
  const int ct = blockIdx.x;
  const int tt = blockIdx.y;
  const int b  = blockIdx.z;
#pragma unroll
  for (int p = 0; p < 2; ++p) {
    const int idx = p * 256 + tid;
    const int row = idx >> 3;
    const int c8  = idx & 7;
    const uint4 v = *(const uint4*)(z + (size_t)(b * 1536 + ct * 64 + row) * 8192 + tt * 64 + c8 * 8);
    unsigned short* tp = &tile[row][c8 * 8];
    tp[0] = (unsigned short)(v.x & 0xffff); tp[1] = (unsigned short)(v.x >> 16);
    tp[2] = (unsigned short)(v.y & 0xffff); tp[3] = (unsigned short)(v.y >> 16);
    tp[4] = (unsigned short)(v.z & 0xffff); tp[5] = (unsigned short)(v.z >> 16);
    tp[6] = (unsigned short)(v.w & 0xffff); tp[7] = (unsigned short)(v.w >> 16);
  }
  __syncthreads();
#pragma unroll
  for (int p = 0; p < 2; ++p) {
    const int idx  = p * 256 + tid;
    const int trow = idx >> 3;
    const int cc   = idx & 7;
    uint4 o;
    o.x = (unsigned)tile[cc * 8 + 0][trow] | ((unsigned)tile[cc * 8 + 1][trow] << 16);
    o.y = (unsigned)tile[cc * 8 + 2][trow] | ((unsigned)tile[cc * 8 + 3][trow] << 16);
    o.z = (unsigned)tile[cc * 8 + 4][trow] | ((unsigned)tile[cc * 8 + 5][trow] << 16);
    o.w = (unsigned)tile[cc * 8 + 6][trow] | ((unsigned)tile[cc * 8 + 7][trow] << 16);
    *(uint4*)(zt + (size_t)(b * 8192 + tt * 64 + trow) * 1536 + ct * 64 + cc * 8) = o;
  }
}

// ---------------------------------------------------------------------------
extern "C" void kernel_launch(void* const* d_in, const int* in_sizes, int n_in,
                              void* d_out, int out_size, void* d_ws, size_t ws_size,
                              hipStream_t stream) {
  const float* u   = (const float*)d_in[0];
  const float* w1  = (const float*)d_in[1];
  const float* b1  = (const float*)d_in[2];
  const float* sw  = (const float*)d_in[3];
  const float* sb  = (const float*)d_in[4];
  const float* km  = (const float*)d_in[5];
  const float* cb  = (const float*)d_in[6];
  const float* w2  = (const float*)d_in[7];
  const float* b2  = (const float*)d_in[8];
  float* outp = (float*)d_out;

  char* ws = (char*)d_ws;
  constexpr size_t OFF_UBF  = 0;
  constexpr size_t OFF_W1   = 25165824;
  constexpr size_t OFF_W2   = 26935296;
  constexpr size_t OFF_UPT  = 29294592;
  constexpr size_t OFF_ZBUF = 67043328;
  constexpr size_t OFF_KF   = 117374976;   // P,Q tables; ztb aliases (dead by then)
  constexpr size_t OFF_ZTB  = 117374976;
  constexpr size_t KF_SZ    = 100663296;   // 1536*8192*8 B
  constexpr size_t OFF_TW   = OFF_KF + KF_SZ;   // 218038272
  constexpr size_t TW_SZ    = 65536;

  unsigned short* u_bf  = (unsigned short*)(ws + OFF_UBF);
  unsigned short* w1_bf = (unsigned short*)(ws + OFF_W1);
  unsigned short* w2_bf = (unsigned short*)(ws + OFF_W2);
  unsigned short* upT   = (unsigned short*)(ws + OFF_UPT);
  unsigned short* zbuf  = (unsigned short*)(ws + OFF_ZBUF);
  uint2*          kfbuf = (uint2*)(ws + OFF_KF);
  float2*         twbuf = (float2*)(ws + OFF_TW);
  unsigned short* ztb   = (unsigned short*)(ws + OFF_ZTB);

  cast_f32_to_bf16<<<12288, 256, 0, stream>>>(u,  u_bf,  12582912);
  cast_f32_to_bf16<<<  864, 256, 0, stream>>>(w1, w1_bf,   884736);
  cast_f32_to_bf16<<< 1152, 256, 0, stream>>>(w2, w2_bf,  1179648);

  dim3 g1(128, 9);
  gemm_bt<1><<<g1, 256, 0, stream>>>(u_bf, w1_bf, b1, upT, 16384, 1152, 768);

  if (ws_size >= OFF_TW + TW_SZ) {
    tw_init_kernel<<<16, 512, 0, stream>>>(twbuf);
    fft_k_kernel<<<1536, 512, 0, stream>>>(km, cb, kfbuf, twbuf);
    hyena_fftconv_split<<<dim3(2, 1536), 512, 0, stream>>>(upT, kfbuf, sw, sb, twbuf, zbuf);
  } else {
    hyena_fftconv_mono<<<1536, 512, 0, stream>>>(upT, km, sw, sb, cb, zbuf);
  }

  transpose_z<<<dim3(24, 128, 2), 256, 0, stream>>>(zbuf, ztb);

  dim3 g2(128, 6);
  gemm_bt<0><<<g2, 256, 0, stream>>>(ztb, w2_bf, b2, outp, 16384, 768, 1536);
}